// Round 1
// baseline (2292.554 us; speedup 1.0000x reference)
//
#include <hip/hip_runtime.h>
#include <hip/hip_bf16.h>
#include <math.h>

#define BB 2
#define NN 2048
#define HH 256
#define WW 256
#define CC 128
#define STATE 256
#define MIDN 6

// workspace layout (float offsets)
#define OFF_X0P   0u
#define OFF_BUF1  1048576u
#define OFF_BUF2  2097152u
#define OFF_BUF3  3145728u
#define OFF_Y     4194304u
#define OFF_W01   5242880u
#define OFF_W02   5308416u
#define OFF_DPTS  5373952u
#define OFF_TVALS 5382144u

// ---------------- bilinear interp + concat + zero-pad to 256 cols ----------------
__global__ void interp_kernel(const float* __restrict__ features,
                              const float* __restrict__ base_point,
                              float* __restrict__ x0p) {
    int idx = blockIdx.x;            // 0..B*N-1
    int b   = idx >> 11;             // / 2048
    int t   = threadIdx.x;           // 0..255
    float xs = base_point[idx * 2 + 0] * (float)WW;
    float ys = base_point[idx * 2 + 1] * (float)HH;
    float x0f = floorf(xs), y0f = floorf(ys);
    float x1f = x0f + 1.f, y1f = y0f + 1.f;
    float w00 = (x1f - xs) * (y1f - ys);
    float w01 = (x1f - xs) * (ys - y0f);
    float w10 = (xs - x0f) * (y1f - ys);
    float w11 = (xs - x0f) * (ys - y0f);
    int X0 = (int)fminf(fmaxf(x0f, 0.f), (float)(WW - 1));
    int X1 = (int)fminf(fmaxf(x1f, 0.f), (float)(WW - 1));
    int Y0 = (int)fminf(fmaxf(y0f, 0.f), (float)(HH - 1));
    int Y1 = (int)fminf(fmaxf(y1f, 0.f), (float)(HH - 1));
    int p00 = Y0 * WW + X0, p01 = Y1 * WW + X0;
    int p10 = Y0 * WW + X1, p11 = Y1 * WW + X1;
    float val = 0.f;
    if (t < CC) {
        const float* f = features + (size_t)(b * CC + t) * (HH * WW);
        val = w00 * f[p00] + w01 * f[p01] + w10 * f[p10] + w11 * f[p11];
    } else if (t == CC) {
        val = base_point[idx * 2 + 0];
    } else if (t == CC + 1) {
        val = base_point[idx * 2 + 1];
    }
    x0p[(size_t)idx * STATE + t] = val;
}

// ---------------- pad w_first [2][130][256] -> two [256][256] (zero rows >=130) ----------------
__global__ void pad_w_first(const float* __restrict__ w_first,
                            float* __restrict__ w01, float* __restrict__ w02) {
    int idx = blockIdx.x * 256 + threadIdx.x;   // 0 .. 2*65536-1
    int k   = idx >> 16;
    int rc  = idx & 65535;
    int row = rc >> 8, col = rc & 255;
    float v = (row < 130) ? w_first[((size_t)k * 130 + row) * 256 + col] : 0.f;
    float* dst = k ? w02 : w01;
    dst[rc] = v;
}

// ---------------- y[b] = adj[b] (2048x2048) @ x[b] (2048x256) ----------------
__global__ __launch_bounds__(256) void adj_gemm(const float* __restrict__ adj,
                                                const float* __restrict__ x,
                                                float* __restrict__ y) {
    __shared__ float As[64][17];
    __shared__ float Bs[16][64];
    int bz = blockIdx.z;
    int rowTile = blockIdx.y * 64;
    int colTile = blockIdx.x * 64;
    const float* A  = adj + (size_t)bz * NN * NN;
    const float* X  = x   + (size_t)bz * NN * STATE;
    float*       Yo = y   + (size_t)bz * NN * STATE;
    int tx = threadIdx.x & 15, ty = threadIdx.x >> 4;   // 16x16 threads, 4x4 each
    float acc[4][4] = {};
    for (int k0 = 0; k0 < NN; k0 += 16) {
        #pragma unroll
        for (int i = 0; i < 4; ++i)
            As[ty + 16 * i][tx] = A[(size_t)(rowTile + ty + 16 * i) * NN + k0 + tx];
        int br = threadIdx.x >> 6, bc = threadIdx.x & 63;
        #pragma unroll
        for (int i = 0; i < 4; ++i)
            Bs[br + 4 * i][bc] = X[(size_t)(k0 + br + 4 * i) * STATE + colTile + bc];
        __syncthreads();
        #pragma unroll
        for (int kk = 0; kk < 16; ++kk) {
            float a[4], bb[4];
            #pragma unroll
            for (int i = 0; i < 4; ++i) a[i] = As[ty * 4 + i][kk];
            #pragma unroll
            for (int j = 0; j < 4; ++j) bb[j] = Bs[kk][tx * 4 + j];
            #pragma unroll
            for (int i = 0; i < 4; ++i)
                #pragma unroll
                for (int j = 0; j < 4; ++j)
                    acc[i][j] += a[i] * bb[j];
        }
        __syncthreads();
    }
    #pragma unroll
    for (int i = 0; i < 4; ++i)
        #pragma unroll
        for (int j = 0; j < 4; ++j)
            Yo[(size_t)(rowTile + ty * 4 + i) * STATE + colTile + tx * 4 + j] = acc[i][j];
}

// ---------------- out = xin@w1 + yin@w2 + b1 + b2 (+res) (relu) ----------------
// xin,yin,out,res: [4096][256]; w1,w2: [256][256]
__global__ __launch_bounds__(256) void fused_w(const float* __restrict__ xin,
                                               const float* __restrict__ yin,
                                               const float* __restrict__ w1,
                                               const float* __restrict__ w2,
                                               const float* __restrict__ b1,
                                               const float* __restrict__ b2,
                                               const float* __restrict__ res,
                                               float* __restrict__ out, int relu) {
    __shared__ float As[64][17];
    __shared__ float Bs[16][64];
    int rowTile = blockIdx.y * 64;
    int colTile = blockIdx.x * 64;
    int tx = threadIdx.x & 15, ty = threadIdx.x >> 4;
    float acc[4][4] = {};
    for (int pass = 0; pass < 2; ++pass) {
        const float* A  = pass ? yin : xin;
        const float* Wm = pass ? w2 : w1;
        for (int k0 = 0; k0 < STATE; k0 += 16) {
            #pragma unroll
            for (int i = 0; i < 4; ++i)
                As[ty + 16 * i][tx] = A[(size_t)(rowTile + ty + 16 * i) * STATE + k0 + tx];
            int br = threadIdx.x >> 6, bc = threadIdx.x & 63;
            #pragma unroll
            for (int i = 0; i < 4; ++i)
                Bs[br + 4 * i][bc] = Wm[(size_t)(k0 + br + 4 * i) * STATE + colTile + bc];
            __syncthreads();
            #pragma unroll
            for (int kk = 0; kk < 16; ++kk) {
                float a[4], bb[4];
                #pragma unroll
                for (int i = 0; i < 4; ++i) a[i] = As[ty * 4 + i][kk];
                #pragma unroll
                for (int j = 0; j < 4; ++j) bb[j] = Bs[kk][tx * 4 + j];
                #pragma unroll
                for (int i = 0; i < 4; ++i)
                    #pragma unroll
                    for (int j = 0; j < 4; ++j)
                        acc[i][j] += a[i] * bb[j];
            }
            __syncthreads();
        }
    }
    #pragma unroll
    for (int i = 0; i < 4; ++i)
        #pragma unroll
        for (int j = 0; j < 4; ++j) {
            int r = rowTile + ty * 4 + i, c = colTile + tx * 4 + j;
            float v = acc[i][j] + b1[c] + b2[c];
            if (res)  v += res[(size_t)r * STATE + c];
            if (relu) v = fmaxf(v, 0.f);
            out[(size_t)r * STATE + c] = v;
        }
}

// ---------------- head: gcn_pred, pred_points, d = gcn_pred*mask ----------------
__global__ void head_kernel(const float* __restrict__ z, const float* __restrict__ w_fc,
                            const float* __restrict__ b_fc, const float* __restrict__ base_point,
                            const float* __restrict__ point_mask, float* __restrict__ out,
                            float* __restrict__ dpts) {
    int row = blockIdx.x * 256 + threadIdx.x;   // 0..4095
    float g0 = b_fc[0], g1 = b_fc[1];
    const float* zr = z + (size_t)row * STATE;
    for (int d = 0; d < STATE; ++d) {
        float v = zr[d];
        g0 += v * w_fc[d * 2 + 0];
        g1 += v * w_fc[d * 2 + 1];
    }
    float m  = point_mask[row];
    float p0 = base_point[row * 2 + 0] + g0 * m;
    float p1 = base_point[row * 2 + 1] + g1 * m;
    out[row * 2 + 0] = p0;
    out[row * 2 + 1] = p1;
    out[2 * BB * NN + row * 2 + 0] = g0;   // gcn_pred block at offset 8192
    out[2 * BB * NN + row * 2 + 1] = g1;
    dpts[row * 2 + 0] = g0 * m;
    dpts[row * 2 + 1] = g1 * m;
}

// ---------------- per-row lap term: t = sqrt(|d - adj@d|^2 + 1e-10) ----------------
__global__ void lap_rows(const float* __restrict__ adj, const float* __restrict__ dpts,
                         float* __restrict__ tvals) {
    int w    = threadIdx.x >> 6;
    int lane = threadIdx.x & 63;
    int row  = blockIdx.x * 4 + w;       // 0..4095
    int b = row >> 11, n = row & 2047;
    const float* ar = adj  + (size_t)b * NN * NN + (size_t)n * NN;
    const float* db = dpts + (size_t)b * NN * 2;
    float s0 = 0.f, s1 = 0.f;
    for (int k = lane; k < NN; k += 64) {
        float a = ar[k];
        s0 += a * db[k * 2 + 0];
        s1 += a * db[k * 2 + 1];
    }
    for (int off = 32; off; off >>= 1) {
        s0 += __shfl_xor(s0, off);
        s1 += __shfl_xor(s1, off);
    }
    if (lane == 0) {
        float e0 = dpts[(size_t)row * 2 + 0] - s0;
        float e1 = dpts[(size_t)row * 2 + 1] - s1;
        tvals[row] = sqrtf(e0 * e0 + e1 * e1 + 1e-10f);
    }
}

__global__ void lap_reduce(const float* __restrict__ tvals, float* __restrict__ outp) {
    __shared__ float sd[256];
    int b = blockIdx.x;
    float s = 0.f;
    for (int i = threadIdx.x; i < NN; i += 256) s += tvals[b * NN + i];
    sd[threadIdx.x] = s;
    __syncthreads();
    for (int o = 128; o; o >>= 1) {
        if (threadIdx.x < o) sd[threadIdx.x] += sd[threadIdx.x + o];
        __syncthreads();
    }
    if (threadIdx.x == 0) outp[b] = sd[0] / (float)NN;
}

extern "C" void kernel_launch(void* const* d_in, const int* in_sizes, int n_in,
                              void* d_out, int out_size, void* d_ws, size_t ws_size,
                              hipStream_t stream) {
    const float* features   = (const float*)d_in[0];
    const float* base_point = (const float*)d_in[1];
    const float* adj        = (const float*)d_in[2];
    const float* point_mask = (const float*)d_in[3];
    const float* w_first    = (const float*)d_in[4];
    const float* b_first    = (const float*)d_in[5];
    const float* w_mid      = (const float*)d_in[6];
    const float* b_mid      = (const float*)d_in[7];
    const float* w_last     = (const float*)d_in[8];
    const float* b_last     = (const float*)d_in[9];
    const float* w_fc       = (const float*)d_in[10];
    const float* b_fc       = (const float*)d_in[11];
    float* out = (float*)d_out;
    float* ws  = (float*)d_ws;

    float* x0p   = ws + OFF_X0P;
    float* bufs[3] = { ws + OFF_BUF1, ws + OFF_BUF2, ws + OFF_BUF3 };
    float* Y     = ws + OFF_Y;
    float* w01   = ws + OFF_W01;
    float* w02   = ws + OFF_W02;
    float* dpts  = ws + OFF_DPTS;
    float* tvals = ws + OFF_TVALS;

    interp_kernel<<<BB * NN, 256, 0, stream>>>(features, base_point, x0p);
    pad_w_first<<<512, 256, 0, stream>>>(w_first, w01, w02);

    int fi = 0;
    auto nb = [&]() { float* p = bufs[fi]; fi = (fi + 1) % 3; return p; };

    dim3 gAdj(STATE / 64, NN / 64, BB);      // 4 x 32 x 2
    dim3 gW(STATE / 64, (BB * NN) / 64);     // 4 x 64

    // first gconv (padded to uniform K=256)
    float* X = nb();
    adj_gemm<<<gAdj, 256, 0, stream>>>(adj, x0p, Y);
    fused_w<<<gW, 256, 0, stream>>>(x0p, Y, w01, w02, b_first, b_first + STATE,
                                    nullptr, X, 0);

    for (int i = 0; i < MIDN; ++i) {
        const float* wm = w_mid + (size_t)i * 4 * STATE * STATE;
        const float* bm = b_mid + (size_t)i * 4 * STATE;
        float* Hb = nb();
        adj_gemm<<<gAdj, 256, 0, stream>>>(adj, X, Y);
        fused_w<<<gW, 256, 0, stream>>>(X, Y, wm, wm + STATE * STATE,
                                        bm, bm + STATE, nullptr, Hb, 1);
        float* Xn = nb();
        adj_gemm<<<gAdj, 256, 0, stream>>>(adj, Hb, Y);
        fused_w<<<gW, 256, 0, stream>>>(Hb, Y, wm + 2 * STATE * STATE, wm + 3 * STATE * STATE,
                                        bm + 2 * STATE, bm + 3 * STATE, X, Xn, 1);
        X = Xn;
    }

    // last gconv
    float* Z = nb();
    adj_gemm<<<gAdj, 256, 0, stream>>>(adj, X, Y);
    fused_w<<<gW, 256, 0, stream>>>(X, Y, w_last, w_last + STATE * STATE,
                                    b_last, b_last + STATE, nullptr, Z, 0);

    head_kernel<<<(BB * NN) / 256, 256, 0, stream>>>(Z, w_fc, b_fc, base_point,
                                                     point_mask, out, dpts);
    lap_rows<<<(BB * NN) / 4, 256, 0, stream>>>(adj, dpts, tvals);
    lap_reduce<<<BB, 256, 0, stream>>>(tvals, out + 2 * 2 * BB * NN);
}

// Round 2
// 483.674 us; speedup vs baseline: 4.7399x; 4.7399x over previous
//
#include <hip/hip_runtime.h>
#include <hip/hip_bf16.h>
#include <math.h>

#define BB 2
#define NN 2048
#define HH 256
#define WW 256
#define CC 128
#define STATE 256
#define MIDN 6

typedef __hip_bfloat16 bf16;
typedef short short8 __attribute__((ext_vector_type(8)));
typedef float f32x4 __attribute__((ext_vector_type(4)));
typedef unsigned short ushort4v __attribute__((ext_vector_type(4)));

__device__ inline float bf2f(unsigned short u) {
    return __uint_as_float(((unsigned int)u) << 16);
}
__device__ inline unsigned short f2bf_bits(float f) {
    __hip_bfloat16 h = __float2bfloat16(f);
    return *reinterpret_cast<unsigned short*>(&h);
}

// ---------------- adj f32 -> bf16 ----------------
__global__ void conv_adj(const float* __restrict__ a, bf16* __restrict__ o) {
    size_t i = ((size_t)blockIdx.x * 256 + threadIdx.x) * 8;
    float4 f0 = *(const float4*)(a + i);
    float4 f1 = *(const float4*)(a + i + 4);
    short8 v;
    v[0] = (short)f2bf_bits(f0.x); v[1] = (short)f2bf_bits(f0.y);
    v[2] = (short)f2bf_bits(f0.z); v[3] = (short)f2bf_bits(f0.w);
    v[4] = (short)f2bf_bits(f1.x); v[5] = (short)f2bf_bits(f1.y);
    v[6] = (short)f2bf_bits(f1.z); v[7] = (short)f2bf_bits(f1.w);
    *(short8*)(o + i) = v;
}

// ---------------- weight transpose f32 [R][256] -> bf16 [256][256] (pad K to 256) ----------------
__global__ void transpose_w(const float* __restrict__ src, bf16* __restrict__ dst, int R) {
    __shared__ float t[32][33];
    int m = blockIdx.z;
    const float* S = src + (size_t)m * R * 256;
    bf16* D = dst + (size_t)m * 65536;
    int c0 = blockIdx.x * 32, r0 = blockIdx.y * 32;
    #pragma unroll
    for (int k = 0; k < 4; ++k) {
        int r = r0 + threadIdx.y + 8 * k;
        t[threadIdx.y + 8 * k][threadIdx.x] = (r < R) ? S[(size_t)r * 256 + c0 + threadIdx.x] : 0.f;
    }
    __syncthreads();
    #pragma unroll
    for (int k = 0; k < 4; ++k) {
        int c = c0 + threadIdx.y + 8 * k;
        D[(size_t)c * 256 + r0 + threadIdx.x] = __float2bfloat16(t[threadIdx.x][threadIdx.y + 8 * k]);
    }
}

// ---------------- x0 transpose bf16 [4096][256] -> [256][4096] ----------------
__global__ void transpose_x0(const bf16* __restrict__ src, bf16* __restrict__ dst) {
    __shared__ bf16 t[32][33];
    int c0 = blockIdx.x * 32, r0 = blockIdx.y * 32;
    #pragma unroll
    for (int k = 0; k < 4; ++k)
        t[threadIdx.y + 8 * k][threadIdx.x] = src[(size_t)(r0 + threadIdx.y + 8 * k) * 256 + c0 + threadIdx.x];
    __syncthreads();
    #pragma unroll
    for (int k = 0; k < 4; ++k)
        dst[(size_t)(c0 + threadIdx.y + 8 * k) * 4096 + r0 + threadIdx.x] = t[threadIdx.x][threadIdx.y + 8 * k];
}

// ---------------- bilinear interp + concat -> x0 bf16 [4096][256] (zero pad feats>=130) ----------------
__global__ void interp_kernel(const float* __restrict__ features,
                              const float* __restrict__ base_point,
                              bf16* __restrict__ x0p) {
    int idx = blockIdx.x;
    int b   = idx >> 11;
    int t   = threadIdx.x;
    float xs = base_point[idx * 2 + 0] * (float)WW;
    float ys = base_point[idx * 2 + 1] * (float)HH;
    float x0f = floorf(xs), y0f = floorf(ys);
    float x1f = x0f + 1.f, y1f = y0f + 1.f;
    float w00 = (x1f - xs) * (y1f - ys);
    float w01 = (x1f - xs) * (ys - y0f);
    float w10 = (xs - x0f) * (y1f - ys);
    float w11 = (xs - x0f) * (ys - y0f);
    int X0 = (int)fminf(fmaxf(x0f, 0.f), (float)(WW - 1));
    int X1 = (int)fminf(fmaxf(x1f, 0.f), (float)(WW - 1));
    int Y0 = (int)fminf(fmaxf(y0f, 0.f), (float)(HH - 1));
    int Y1 = (int)fminf(fmaxf(y1f, 0.f), (float)(HH - 1));
    int p00 = Y0 * WW + X0, p01 = Y1 * WW + X0;
    int p10 = Y0 * WW + X1, p11 = Y1 * WW + X1;
    float val = 0.f;
    if (t < CC) {
        const float* f = features + (size_t)(b * CC + t) * (HH * WW);
        val = w00 * f[p00] + w01 * f[p01] + w10 * f[p10] + w11 * f[p11];
    } else if (t == CC) {
        val = base_point[idx * 2 + 0];
    } else if (t == CC + 1) {
        val = base_point[idx * 2 + 1];
    }
    x0p[(size_t)idx * 256 + t] = __float2bfloat16(val);
}

// ================= MFMA adj gemm: Y[kh] = adj[:, khalf] @ x[khalf, :] =================
// grid (2, 32, 4): x=coltile(128 feats), y=rowtile(64 rows), z=b*2+kh. block 256.
__global__ __launch_bounds__(256) void adj_gemm_b(const bf16* __restrict__ adjB,
                                                  const bf16* __restrict__ xT,
                                                  bf16* __restrict__ Y0,
                                                  bf16* __restrict__ Y1) {
    __shared__ bf16 Al[64 * 64];    // [row][k] 128B rows, XOR swizzled
    __shared__ bf16 Bl[128 * 64];   // [feat][k]
    int tid = threadIdx.x;
    int ct = blockIdx.x, rt = blockIdx.y, bz = blockIdx.z;
    int b = bz >> 1, kh = bz & 1;
    const bf16* Aadj = adjB + (size_t)b * NN * NN + (size_t)(rt * 64) * NN + kh * 1024;
    const bf16* Bx   = xT + (size_t)(ct * 128) * 4096 + b * NN + kh * 1024;
    bf16* Yo = kh ? Y1 : Y0;
    int lane = tid & 63, w = tid >> 6;
    int wr = w >> 1, wc = w & 1;
    int row16 = lane & 15, kg = lane >> 4;
    f32x4 acc[2][4] = {};
    for (int it = 0; it < 16; ++it) {
        int k0 = it * 64;
        #pragma unroll
        for (int rnd = 0; rnd < 2; ++rnd) {
            int d = tid * 16 + rnd * 4096;
            int row = d >> 7, cb = d & 127;
            int sc = (cb ^ ((row & 7) << 4)) >> 1;
            __builtin_amdgcn_global_load_lds(
                (const __attribute__((address_space(1))) void*)(Aadj + (size_t)row * NN + k0 + sc),
                (__attribute__((address_space(3))) void*)((char*)Al + (w << 10) + rnd * 4096),
                16, 0, 0);
        }
        #pragma unroll
        for (int rnd = 0; rnd < 4; ++rnd) {
            int d = tid * 16 + rnd * 4096;
            int row = d >> 7, cb = d & 127;
            int sc = (cb ^ ((row & 7) << 4)) >> 1;
            __builtin_amdgcn_global_load_lds(
                (const __attribute__((address_space(1))) void*)(Bx + (size_t)row * 4096 + k0 + sc),
                (__attribute__((address_space(3))) void*)((char*)Bl + (w << 10) + rnd * 4096),
                16, 0, 0);
        }
        asm volatile("s_waitcnt vmcnt(0)" ::: "memory");
        __syncthreads();
        #pragma unroll
        for (int kk = 0; kk < 2; ++kk) {
            short8 a[2], bfr[4];
            #pragma unroll
            for (int mf = 0; mf < 2; ++mf) {
                int row = wr * 32 + mf * 16 + row16;
                int byte = row * 128 + (((kk * 64) + kg * 16) ^ ((row & 7) << 4));
                a[mf] = *(const short8*)((const char*)Al + byte);
            }
            #pragma unroll
            for (int nf = 0; nf < 4; ++nf) {
                int fr = wc * 64 + nf * 16 + row16;
                int byte = fr * 128 + (((kk * 64) + kg * 16) ^ ((fr & 7) << 4));
                bfr[nf] = *(const short8*)((const char*)Bl + byte);
            }
            #pragma unroll
            for (int mf = 0; mf < 2; ++mf)
                #pragma unroll
                for (int nf = 0; nf < 4; ++nf)
                    acc[mf][nf] = __builtin_amdgcn_mfma_f32_16x16x32_bf16(a[mf], bfr[nf], acc[mf][nf], 0, 0, 0);
        }
        __syncthreads();
    }
    // epilogue: Y row-major [4096][256]
    #pragma unroll
    for (int mf = 0; mf < 2; ++mf) {
        #pragma unroll
        for (int nf = 0; nf < 4; ++nf) {
            int c = ct * 128 + wc * 64 + nf * 16 + row16;
            int rb = b * NN + rt * 64 + wr * 32 + mf * 16 + kg * 4;
            #pragma unroll
            for (int j = 0; j < 4; ++j)
                Yo[(size_t)(rb + j) * 256 + c] = __float2bfloat16(acc[mf][nf][j]);
        }
    }
}

// ================= MFMA fused: out = a0@b0t' + a1@b1t' + a2@b1t' + bias1 + bias2 (+res)(relu) =================
// a*: [4096][256] bf16 row-major; b*t: [256 outfeat][256 infeat] bf16 (transposed weights)
// writes outR [4096][256] and outT [256][4096]
__global__ __launch_bounds__(256) void fused_w_b(const bf16* __restrict__ a0,
                                                 const bf16* __restrict__ a1,
                                                 const bf16* __restrict__ a2,
                                                 const bf16* __restrict__ b0t,
                                                 const bf16* __restrict__ b1t,
                                                 const float* __restrict__ bias1,
                                                 const float* __restrict__ bias2,
                                                 const bf16* __restrict__ res,
                                                 bf16* __restrict__ outR,
                                                 bf16* __restrict__ outT,
                                                 int relu) {
    __shared__ bf16 Al[64 * 64];
    __shared__ bf16 Bl[128 * 64];
    int tid = threadIdx.x;
    int ct = blockIdx.x, rt = blockIdx.y;
    int lane = tid & 63, w = tid >> 6;
    int wr = w >> 1, wc = w & 1;
    int row16 = lane & 15, kg = lane >> 4;
    f32x4 acc[2][4] = {};
    #pragma unroll 1
    for (int p = 0; p < 3; ++p) {
        const bf16* Ap = (p == 0) ? a0 : ((p == 1) ? a1 : a2);
        const bf16* Bp = (p == 0) ? b0t : b1t;
        const bf16* Abase = Ap + (size_t)(rt * 64) * 256;
        const bf16* Bbase = Bp + (size_t)(ct * 128) * 256;
        #pragma unroll 1
        for (int it = 0; it < 4; ++it) {
            int k0 = it * 64;
            #pragma unroll
            for (int rnd = 0; rnd < 2; ++rnd) {
                int d = tid * 16 + rnd * 4096;
                int row = d >> 7, cb = d & 127;
                int sc = (cb ^ ((row & 7) << 4)) >> 1;
                __builtin_amdgcn_global_load_lds(
                    (const __attribute__((address_space(1))) void*)(Abase + (size_t)row * 256 + k0 + sc),
                    (__attribute__((address_space(3))) void*)((char*)Al + (w << 10) + rnd * 4096),
                    16, 0, 0);
            }
            #pragma unroll
            for (int rnd = 0; rnd < 4; ++rnd) {
                int d = tid * 16 + rnd * 4096;
                int row = d >> 7, cb = d & 127;
                int sc = (cb ^ ((row & 7) << 4)) >> 1;
                __builtin_amdgcn_global_load_lds(
                    (const __attribute__((address_space(1))) void*)(Bbase + (size_t)row * 256 + k0 + sc),
                    (__attribute__((address_space(3))) void*)((char*)Bl + (w << 10) + rnd * 4096),
                    16, 0, 0);
            }
            asm volatile("s_waitcnt vmcnt(0)" ::: "memory");
            __syncthreads();
            #pragma unroll
            for (int kk = 0; kk < 2; ++kk) {
                short8 a[2], bfr[4];
                #pragma unroll
                for (int mf = 0; mf < 2; ++mf) {
                    int row = wr * 32 + mf * 16 + row16;
                    int byte = row * 128 + (((kk * 64) + kg * 16) ^ ((row & 7) << 4));
                    a[mf] = *(const short8*)((const char*)Al + byte);
                }
                #pragma unroll
                for (int nf = 0; nf < 4; ++nf) {
                    int fr = wc * 64 + nf * 16 + row16;
                    int byte = fr * 128 + (((kk * 64) + kg * 16) ^ ((fr & 7) << 4));
                    bfr[nf] = *(const short8*)((const char*)Bl + byte);
                }
                #pragma unroll
                for (int mf = 0; mf < 2; ++mf)
                    #pragma unroll
                    for (int nf = 0; nf < 4; ++nf)
                        acc[mf][nf] = __builtin_amdgcn_mfma_f32_16x16x32_bf16(a[mf], bfr[nf], acc[mf][nf], 0, 0, 0);
            }
            __syncthreads();
        }
    }
    #pragma unroll
    for (int mf = 0; mf < 2; ++mf) {
        #pragma unroll
        for (int nf = 0; nf < 4; ++nf) {
            int c = ct * 128 + wc * 64 + nf * 16 + row16;
            int rb = rt * 64 + wr * 32 + mf * 16 + kg * 4;
            float badd = bias1[c] + bias2[c];
            ushort4v pack;
            #pragma unroll
            for (int j = 0; j < 4; ++j) {
                int r = rb + j;
                float v = acc[mf][nf][j] + badd;
                if (res) v += bf2f(*reinterpret_cast<const unsigned short*>(&res[(size_t)r * 256 + c]));
                if (relu) v = fmaxf(v, 0.f);
                unsigned short us = f2bf_bits(v);
                *reinterpret_cast<unsigned short*>(&outR[(size_t)r * 256 + c]) = us;
                pack[j] = us;
            }
            *(ushort4v*)(outT + (size_t)c * 4096 + rb) = pack;
        }
    }
}

// ---------------- head ----------------
__global__ void head_kernel(const bf16* __restrict__ z, const float* __restrict__ w_fc,
                            const float* __restrict__ b_fc, const float* __restrict__ base_point,
                            const float* __restrict__ point_mask, float* __restrict__ out,
                            float* __restrict__ dpts) {
    int row = blockIdx.x * 256 + threadIdx.x;
    float g0 = b_fc[0], g1 = b_fc[1];
    const bf16* zr = z + (size_t)row * 256;
    for (int d = 0; d < 256; d += 8) {
        short8 v8 = *(const short8*)(zr + d);
        #pragma unroll
        for (int j = 0; j < 8; ++j) {
            float v = bf2f((unsigned short)v8[j]);
            g0 += v * w_fc[(d + j) * 2 + 0];
            g1 += v * w_fc[(d + j) * 2 + 1];
        }
    }
    float m  = point_mask[row];
    float p0 = base_point[row * 2 + 0] + g0 * m;
    float p1 = base_point[row * 2 + 1] + g1 * m;
    out[row * 2 + 0] = p0;
    out[row * 2 + 1] = p1;
    out[2 * BB * NN + row * 2 + 0] = g0;
    out[2 * BB * NN + row * 2 + 1] = g1;
    dpts[row * 2 + 0] = g0 * m;
    dpts[row * 2 + 1] = g1 * m;
}

// ---------------- lap (f32, uses original adj) ----------------
__global__ void lap_rows(const float* __restrict__ adj, const float* __restrict__ dpts,
                         float* __restrict__ tvals) {
    int w    = threadIdx.x >> 6;
    int lane = threadIdx.x & 63;
    int row  = blockIdx.x * 4 + w;
    int b = row >> 11, n = row & 2047;
    const float* ar = adj  + (size_t)b * NN * NN + (size_t)n * NN;
    const float* db = dpts + (size_t)b * NN * 2;
    float s0 = 0.f, s1 = 0.f;
    for (int k = lane; k < NN; k += 64) {
        float a = ar[k];
        s0 += a * db[k * 2 + 0];
        s1 += a * db[k * 2 + 1];
    }
    for (int off = 32; off; off >>= 1) {
        s0 += __shfl_xor(s0, off);
        s1 += __shfl_xor(s1, off);
    }
    if (lane == 0) {
        float e0 = dpts[(size_t)row * 2 + 0] - s0;
        float e1 = dpts[(size_t)row * 2 + 1] - s1;
        tvals[row] = sqrtf(e0 * e0 + e1 * e1 + 1e-10f);
    }
}

__global__ void lap_reduce(const float* __restrict__ tvals, float* __restrict__ outp) {
    __shared__ float sd[256];
    int b = blockIdx.x;
    float s = 0.f;
    for (int i = threadIdx.x; i < NN; i += 256) s += tvals[b * NN + i];
    sd[threadIdx.x] = s;
    __syncthreads();
    for (int o = 128; o; o >>= 1) {
        if (threadIdx.x < o) sd[threadIdx.x] += sd[threadIdx.x + o];
        __syncthreads();
    }
    if (threadIdx.x == 0) outp[b] = sd[0] / (float)NN;
}

extern "C" void kernel_launch(void* const* d_in, const int* in_sizes, int n_in,
                              void* d_out, int out_size, void* d_ws, size_t ws_size,
                              hipStream_t stream) {
    const float* features   = (const float*)d_in[0];
    const float* base_point = (const float*)d_in[1];
    const float* adj        = (const float*)d_in[2];
    const float* point_mask = (const float*)d_in[3];
    const float* w_first    = (const float*)d_in[4];
    const float* b_first    = (const float*)d_in[5];
    const float* w_mid      = (const float*)d_in[6];
    const float* b_mid      = (const float*)d_in[7];
    const float* w_last     = (const float*)d_in[8];
    const float* b_last     = (const float*)d_in[9];
    const float* w_fc       = (const float*)d_in[10];
    const float* b_fc       = (const float*)d_in[11];
    float* out = (float*)d_out;
    char* W = (char*)d_ws;

    bf16* adjB = (bf16*)W;                              // 16,777,216 B
    bf16* wT   = (bf16*)(W + 16777216);                 // 28 * 131072 B
    bf16* xr0  = (bf16*)(W + 20447232);
    bf16* xr1  = (bf16*)(W + 22544384);
    bf16* xt0  = (bf16*)(W + 24641536);
    bf16* xt1  = (bf16*)(W + 26738688);
    bf16* Y0   = (bf16*)(W + 28835840);
    bf16* Y1   = (bf16*)(W + 30932992);
    float* dpts  = (float*)(W + 33030144);
    float* tvals = (float*)(W + 33046528);

    bf16* xr[2] = { xr0, xr1 };
    bf16* xt[2] = { xt0, xt1 };

    conv_adj<<<4096, 256, 0, stream>>>(adj, adjB);
    transpose_w<<<dim3(8, 8, 2),  dim3(32, 8), 0, stream>>>(w_first, wT, 130);
    transpose_w<<<dim3(8, 8, 24), dim3(32, 8), 0, stream>>>(w_mid, wT + 2 * 65536, 256);
    transpose_w<<<dim3(8, 8, 2),  dim3(32, 8), 0, stream>>>(w_last, wT + 26 * 65536, 256);
    interp_kernel<<<BB * NN, 256, 0, stream>>>(features, base_point, xr[0]);
    transpose_x0<<<dim3(8, 128), dim3(32, 8), 0, stream>>>(xr[0], xt[0]);

    dim3 gAdj(2, 32, 4);
    dim3 gW(2, 64);
    int cur = 0;

    // first gconv
    adj_gemm_b<<<gAdj, 256, 0, stream>>>(adjB, xt[cur], Y0, Y1);
    fused_w_b<<<gW, 256, 0, stream>>>(xr[cur], Y0, Y1, wT, wT + 65536,
                                      b_first, b_first + 256, nullptr,
                                      xr[1 - cur], xt[1 - cur], 0);
    cur = 1 - cur;

    for (int i = 0; i < MIDN; ++i) {
        bf16* w1t = wT + (size_t)(2 + 4 * i) * 65536;
        bf16* w2t = w1t + 65536;
        bf16* w3t = w1t + 2 * 65536;
        bf16* w4t = w1t + 3 * 65536;
        const float* bm = b_mid + (size_t)i * 1024;
        int o = 1 - cur;
        adj_gemm_b<<<gAdj, 256, 0, stream>>>(adjB, xt[cur], Y0, Y1);
        fused_w_b<<<gW, 256, 0, stream>>>(xr[cur], Y0, Y1, w1t, w2t,
                                          bm, bm + 256, nullptr, xr[o], xt[o], 1);
        adj_gemm_b<<<gAdj, 256, 0, stream>>>(adjB, xt[o], Y0, Y1);
        fused_w_b<<<gW, 256, 0, stream>>>(xr[o], Y0, Y1, w3t, w4t,
                                          bm + 512, bm + 768, xr[cur], xr[cur], xt[cur], 1);
        // cur unchanged: block output back in slot cur
    }

    // last gconv
    adj_gemm_b<<<gAdj, 256, 0, stream>>>(adjB, xt[cur], Y0, Y1);
    fused_w_b<<<gW, 256, 0, stream>>>(xr[cur], Y0, Y1, wT + 26 * 65536, wT + 27 * 65536,
                                      b_last, b_last + 256, nullptr,
                                      xr[1 - cur], xt[1 - cur], 0);
    cur = 1 - cur;

    head_kernel<<<(BB * NN) / 256, 256, 0, stream>>>(xr[cur], w_fc, b_fc, base_point,
                                                     point_mask, out, dpts);
    lap_rows<<<(BB * NN) / 4, 256, 0, stream>>>(adj, dpts, tvals);
    lap_reduce<<<BB, 256, 0, stream>>>(tvals, out + 2 * 2 * BB * NN);
}

// Round 3
// 376.593 us; speedup vs baseline: 6.0876x; 1.2843x over previous
//
#include <hip/hip_runtime.h>
#include <hip/hip_bf16.h>
#include <math.h>

#define BB 2
#define NN 2048
#define HH 256
#define WW 256
#define CC 128
#define MIDN 6

typedef __hip_bfloat16 bf16;
typedef short short8 __attribute__((ext_vector_type(8)));
typedef float f32x4 __attribute__((ext_vector_type(4)));
typedef unsigned short ushort4v __attribute__((ext_vector_type(4)));

__device__ inline float bf2f(unsigned short u) {
    return __uint_as_float(((unsigned int)u) << 16);
}
__device__ inline unsigned short f2bf_bits(float f) {
    __hip_bfloat16 h = __float2bfloat16(f);
    return *reinterpret_cast<unsigned short*>(&h);
}

// ======== prep: adj f32->bf16 (blocks 0..4095) | interp (4096..8191) | weight transpose (8192..9983) ========
__global__ void prep_kernel(const float* __restrict__ adj, bf16* __restrict__ adjB,
                            const float* __restrict__ features, const float* __restrict__ base_point,
                            bf16* __restrict__ x0p,
                            const float* __restrict__ w_first, const float* __restrict__ w_mid,
                            const float* __restrict__ w_last, bf16* __restrict__ wT) {
    __shared__ float tbuf[32][33];
    int bid = blockIdx.x;
    int t = threadIdx.x;
    if (bid < 4096) {
        size_t i = ((size_t)bid * 256 + t) * 8;
        float4 f0 = *(const float4*)(adj + i);
        float4 f1 = *(const float4*)(adj + i + 4);
        short8 v;
        v[0] = (short)f2bf_bits(f0.x); v[1] = (short)f2bf_bits(f0.y);
        v[2] = (short)f2bf_bits(f0.z); v[3] = (short)f2bf_bits(f0.w);
        v[4] = (short)f2bf_bits(f1.x); v[5] = (short)f2bf_bits(f1.y);
        v[6] = (short)f2bf_bits(f1.z); v[7] = (short)f2bf_bits(f1.w);
        *(short8*)(adjB + i) = v;
    } else if (bid < 8192) {
        int idx = bid - 4096;               // 0..B*N-1
        int b   = idx >> 11;
        float xs = base_point[idx * 2 + 0] * (float)WW;
        float ys = base_point[idx * 2 + 1] * (float)HH;
        float x0f = floorf(xs), y0f = floorf(ys);
        float x1f = x0f + 1.f, y1f = y0f + 1.f;
        float w00 = (x1f - xs) * (y1f - ys);
        float w01 = (x1f - xs) * (ys - y0f);
        float w10 = (xs - x0f) * (y1f - ys);
        float w11 = (xs - x0f) * (ys - y0f);
        int X0 = (int)fminf(fmaxf(x0f, 0.f), (float)(WW - 1));
        int X1 = (int)fminf(fmaxf(x1f, 0.f), (float)(WW - 1));
        int Y0 = (int)fminf(fmaxf(y0f, 0.f), (float)(HH - 1));
        int Y1 = (int)fminf(fmaxf(y1f, 0.f), (float)(HH - 1));
        int p00 = Y0 * WW + X0, p01 = Y1 * WW + X0;
        int p10 = Y0 * WW + X1, p11 = Y1 * WW + X1;
        float val = 0.f;
        if (t < CC) {
            const float* f = features + (size_t)(b * CC + t) * (HH * WW);
            val = w00 * f[p00] + w01 * f[p01] + w10 * f[p10] + w11 * f[p11];
        } else if (t == CC) {
            val = base_point[idx * 2 + 0];
        } else if (t == CC + 1) {
            val = base_point[idx * 2 + 1];
        }
        x0p[(size_t)idx * 256 + t] = __float2bfloat16(val);
    } else {
        int idx = bid - 8192;               // 0..1791
        int m   = idx >> 6;                 // matrix 0..27
        int sub = idx & 63;
        int bx = sub & 7, by = sub >> 3;
        const float* S; int R;
        if (m < 2)       { S = w_first + (size_t)m * 130 * 256; R = 130; }
        else if (m < 26) { S = w_mid + (size_t)(m - 2) * 65536; R = 256; }
        else             { S = w_last + (size_t)(m - 26) * 65536; R = 256; }
        bf16* D = wT + (size_t)m * 65536;
        int tx = t & 31, ty = t >> 5;
        int c0 = bx * 32, r0 = by * 32;
        #pragma unroll
        for (int k = 0; k < 4; ++k) {
            int r = r0 + ty + 8 * k;
            tbuf[ty + 8 * k][tx] = (r < R) ? S[(size_t)r * 256 + c0 + tx] : 0.f;
        }
        __syncthreads();
        #pragma unroll
        for (int k = 0; k < 4; ++k) {
            int c = c0 + ty + 8 * k;
            D[(size_t)c * 256 + r0 + tx] = __float2bfloat16(tbuf[tx][ty + 8 * k]);
        }
    }
}

// ======== S: x = combine(gprev + v0 + v1 + b1 + b2 [+res][relu]) ; [g1|g2T] = x @ wcat ========
// grid (4, 128): ct = 128-outfeat tile of 512, rt = 32-row tile of 4096. 256 threads.
__global__ __launch_bounds__(256) void s_kernel(const bf16* __restrict__ gprev,
                                                const bf16* __restrict__ v0,
                                                const bf16* __restrict__ v1,
                                                const float* __restrict__ bias1,
                                                const float* __restrict__ bias2,
                                                const bf16* __restrict__ res,
                                                int relu,
                                                const bf16* __restrict__ wcat,
                                                bf16* __restrict__ xR,
                                                bf16* __restrict__ g1out,
                                                bf16* __restrict__ g2T) {
    __shared__ bf16 Al[32 * 64];    // 4 KB, 128B rows, XOR swizzled
    __shared__ bf16 Bl[128 * 64];   // 16 KB
    int tid = threadIdx.x;
    int ct = blockIdx.x, rt = blockIdx.y;
    int lane = tid & 63, w = tid >> 6;
    int wr = w >> 1, wc = w & 1;       // wave: 16 rows x 64 outfeats
    int row16 = lane & 15, kg = lane >> 4;
    f32x4 acc[4] = {};
    for (int it = 0; it < 4; ++it) {
        // ---- A: combine + swizzled ds_write (one b128/thread) ----
        {
            int d = tid * 16;
            int row = d >> 7;              // 0..31
            int cb = d & 127;
            int gcol = it * 64 + (cb >> 1);
            int ridx = rt * 32 + row;
            short8 gv = *(const short8*)(gprev + (size_t)ridx * 256 + gcol);
            short8 pk;
            if (v0) {
                short8 a0 = *(const short8*)(v0 + (size_t)ridx * 256 + gcol);
                short8 a1 = *(const short8*)(v1 + (size_t)ridx * 256 + gcol);
                short8 rv = {};
                if (res) rv = *(const short8*)(res + (size_t)ridx * 256 + gcol);
                #pragma unroll
                for (int j = 0; j < 8; ++j) {
                    float f = bf2f((unsigned short)gv[j]) + bf2f((unsigned short)a0[j])
                            + bf2f((unsigned short)a1[j]) + bias1[gcol + j] + bias2[gcol + j];
                    if (res)  f += bf2f((unsigned short)rv[j]);
                    if (relu) f = fmaxf(f, 0.f);
                    pk[j] = (short)f2bf_bits(f);
                }
            } else {
                pk = gv;
            }
            if (ct == 0) *(short8*)(xR + (size_t)ridx * 256 + gcol) = pk;
            int byte = row * 128 + (cb ^ ((row & 7) << 4));
            *(short8*)((char*)Al + byte) = pk;
        }
        // ---- B: weights via global_load_lds (pre-swizzled source) ----
        #pragma unroll
        for (int rnd = 0; rnd < 4; ++rnd) {
            int d = tid * 16 + rnd * 4096;
            int row = d >> 7;              // outfeat-in-tile 0..127
            int cb = d & 127;
            int sc = (cb ^ ((row & 7) << 4)) >> 1;
            __builtin_amdgcn_global_load_lds(
                (const __attribute__((address_space(1))) void*)(wcat + (size_t)(ct * 128 + row) * 256 + it * 64 + sc),
                (__attribute__((address_space(3))) void*)((char*)Bl + (w << 10) + rnd * 4096),
                16, 0, 0);
        }
        asm volatile("s_waitcnt vmcnt(0)" ::: "memory");
        __syncthreads();
        #pragma unroll
        for (int kk = 0; kk < 2; ++kk) {
            int arow = wr * 16 + row16;
            int abyte = arow * 128 + (((kk * 64) + kg * 16) ^ ((arow & 7) << 4));
            short8 a = *(const short8*)((const char*)Al + abyte);
            #pragma unroll
            for (int nf = 0; nf < 4; ++nf) {
                int fr = wc * 64 + nf * 16 + row16;
                int byte = fr * 128 + (((kk * 64) + kg * 16) ^ ((fr & 7) << 4));
                short8 bfr = *(const short8*)((const char*)Bl + byte);
                acc[nf] = __builtin_amdgcn_mfma_f32_16x16x32_bf16(a, bfr, acc[nf], 0, 0, 0);
            }
        }
        __syncthreads();
    }
    int cbase = ct * 128 + wc * 64;
    int rb = rt * 32 + wr * 16 + kg * 4;
    if (cbase < 256) {
        #pragma unroll
        for (int nf = 0; nf < 4; ++nf) {
            int c = cbase + nf * 16 + row16;
            #pragma unroll
            for (int j = 0; j < 4; ++j)
                *reinterpret_cast<unsigned short*>(&g1out[(size_t)(rb + j) * 256 + c]) = f2bf_bits(acc[nf][j]);
        }
    } else {
        #pragma unroll
        for (int nf = 0; nf < 4; ++nf) {
            int c = cbase - 256 + nf * 16 + row16;
            ushort4v pk;
            #pragma unroll
            for (int j = 0; j < 4; ++j) pk[j] = f2bf_bits(acc[nf][j]);
            *(ushort4v*)(g2T + (size_t)c * 4096 + rb) = pk;
        }
    }
}

// ======== B: Y[kh] = adj[:, khalf] @ g2 — split-K=2, 64x64 tiles ========
// grid (4, 32, 4): ct 64-col, rt 64-row, z = b*2+kh. 256 threads.
__global__ __launch_bounds__(256) void adjb_kernel(const bf16* __restrict__ adjB,
                                                   const bf16* __restrict__ g2T,
                                                   bf16* __restrict__ Y0,
                                                   bf16* __restrict__ Y1) {
    __shared__ bf16 Al[64 * 64];
    __shared__ bf16 Bl[64 * 64];
    int tid = threadIdx.x;
    int ct = blockIdx.x, rt = blockIdx.y, bz = blockIdx.z;
    int b = bz >> 1, kh = bz & 1;
    const bf16* Aadj = adjB + (size_t)b * NN * NN + (size_t)(rt * 64) * NN + kh * 1024;
    const bf16* Bg   = g2T + (size_t)(ct * 64) * 4096 + b * NN + kh * 1024;
    bf16* Yo = kh ? Y1 : Y0;
    int lane = tid & 63, w = tid >> 6;
    int wr = w >> 1, wc = w & 1;       // wave: 32 rows x 32 cols
    int row16 = lane & 15, kg = lane >> 4;
    f32x4 acc[2][2] = {};
    for (int it = 0; it < 16; ++it) {
        int k0 = it * 64;
        #pragma unroll
        for (int rnd = 0; rnd < 2; ++rnd) {
            int d = tid * 16 + rnd * 4096;
            int row = d >> 7, cb = d & 127;
            int sc = (cb ^ ((row & 7) << 4)) >> 1;
            __builtin_amdgcn_global_load_lds(
                (const __attribute__((address_space(1))) void*)(Aadj + (size_t)row * NN + k0 + sc),
                (__attribute__((address_space(3))) void*)((char*)Al + (w << 10) + rnd * 4096),
                16, 0, 0);
        }
        #pragma unroll
        for (int rnd = 0; rnd < 2; ++rnd) {
            int d = tid * 16 + rnd * 4096;
            int row = d >> 7, cb = d & 127;
            int sc = (cb ^ ((row & 7) << 4)) >> 1;
            __builtin_amdgcn_global_load_lds(
                (const __attribute__((address_space(1))) void*)(Bg + (size_t)row * 4096 + k0 + sc),
                (__attribute__((address_space(3))) void*)((char*)Bl + (w << 10) + rnd * 4096),
                16, 0, 0);
        }
        asm volatile("s_waitcnt vmcnt(0)" ::: "memory");
        __syncthreads();
        #pragma unroll
        for (int kk = 0; kk < 2; ++kk) {
            short8 a[2], bfr[2];
            #pragma unroll
            for (int mf = 0; mf < 2; ++mf) {
                int row = wr * 32 + mf * 16 + row16;
                int byte = row * 128 + (((kk * 64) + kg * 16) ^ ((row & 7) << 4));
                a[mf] = *(const short8*)((const char*)Al + byte);
            }
            #pragma unroll
            for (int nf = 0; nf < 2; ++nf) {
                int fr = wc * 32 + nf * 16 + row16;
                int byte = fr * 128 + (((kk * 64) + kg * 16) ^ ((fr & 7) << 4));
                bfr[nf] = *(const short8*)((const char*)Bl + byte);
            }
            #pragma unroll
            for (int mf = 0; mf < 2; ++mf)
                #pragma unroll
                for (int nf = 0; nf < 2; ++nf)
                    acc[mf][nf] = __builtin_amdgcn_mfma_f32_16x16x32_bf16(a[mf], bfr[nf], acc[mf][nf], 0, 0, 0);
        }
        __syncthreads();
    }
    #pragma unroll
    for (int mf = 0; mf < 2; ++mf) {
        #pragma unroll
        for (int nf = 0; nf < 2; ++nf) {
            int c  = ct * 64 + wc * 32 + nf * 16 + row16;
            int r0 = b * NN + rt * 64 + wr * 32 + mf * 16 + kg * 4;
            #pragma unroll
            for (int j = 0; j < 4; ++j)
                *reinterpret_cast<unsigned short*>(&Yo[(size_t)(r0 + j) * 256 + c]) = f2bf_bits(acc[mf][nf][j]);
        }
    }
}

// ======== head: z = g1 + Y0 + Y1 + b_last ; gcn_pred = z@w_fc + b_fc ; outputs ========
__global__ void head_kernel(const bf16* __restrict__ g1, const bf16* __restrict__ Y0,
                            const bf16* __restrict__ Y1, const float* __restrict__ b_last,
                            const float* __restrict__ w_fc, const float* __restrict__ b_fc,
                            const float* __restrict__ base_point, const float* __restrict__ point_mask,
                            float* __restrict__ out, float* __restrict__ dpts) {
    int row = blockIdx.x * 256 + threadIdx.x;
    float s0 = b_fc[0], s1 = b_fc[1];
    for (int d = 0; d < 256; d += 8) {
        short8 a = *(const short8*)(g1 + (size_t)row * 256 + d);
        short8 u = *(const short8*)(Y0 + (size_t)row * 256 + d);
        short8 v = *(const short8*)(Y1 + (size_t)row * 256 + d);
        #pragma unroll
        for (int j = 0; j < 8; ++j) {
            float z = bf2f((unsigned short)a[j]) + bf2f((unsigned short)u[j])
                    + bf2f((unsigned short)v[j]) + b_last[d + j] + b_last[256 + d + j];
            s0 += z * w_fc[(d + j) * 2 + 0];
            s1 += z * w_fc[(d + j) * 2 + 1];
        }
    }
    float m  = point_mask[row];
    float p0 = base_point[row * 2 + 0] + s0 * m;
    float p1 = base_point[row * 2 + 1] + s1 * m;
    out[row * 2 + 0] = p0;
    out[row * 2 + 1] = p1;
    out[2 * BB * NN + row * 2 + 0] = s0;
    out[2 * BB * NN + row * 2 + 1] = s1;
    dpts[row * 2 + 0] = s0 * m;
    dpts[row * 2 + 1] = s1 * m;
}

// ======== lap: t = sqrt(|d - adj@d|^2 + 1e-10) per row, then mean per batch ========
__global__ void lap_rows(const bf16* __restrict__ adjB, const float* __restrict__ dpts,
                         float* __restrict__ tvals) {
    int w    = threadIdx.x >> 6;
    int lane = threadIdx.x & 63;
    int row  = blockIdx.x * 4 + w;
    int b = row >> 11, n = row & 2047;
    const bf16* ar = adjB + (size_t)b * NN * NN + (size_t)n * NN;
    const float* db = dpts + (size_t)b * NN * 2;
    float s0 = 0.f, s1 = 0.f;
    for (int k4 = 0; k4 < 4; ++k4) {
        int k = k4 * 512 + lane * 8;
        short8 av = *(const short8*)(ar + k);
        #pragma unroll
        for (int j = 0; j < 8; ++j) {
            float a = bf2f((unsigned short)av[j]);
            float2 dv = *(const float2*)(db + (k + j) * 2);
            s0 += a * dv.x;
            s1 += a * dv.y;
        }
    }
    for (int off = 32; off; off >>= 1) {
        s0 += __shfl_xor(s0, off);
        s1 += __shfl_xor(s1, off);
    }
    if (lane == 0) {
        float e0 = dpts[(size_t)row * 2 + 0] - s0;
        float e1 = dpts[(size_t)row * 2 + 1] - s1;
        tvals[row] = sqrtf(e0 * e0 + e1 * e1 + 1e-10f);
    }
}

__global__ void lap_reduce(const float* __restrict__ tvals, float* __restrict__ outp) {
    __shared__ float sd[256];
    int b = blockIdx.x;
    float s = 0.f;
    for (int i = threadIdx.x; i < NN; i += 256) s += tvals[b * NN + i];
    sd[threadIdx.x] = s;
    __syncthreads();
    for (int o = 128; o; o >>= 1) {
        if (threadIdx.x < o) sd[threadIdx.x] += sd[threadIdx.x + o];
        __syncthreads();
    }
    if (threadIdx.x == 0) outp[b] = sd[0] / (float)NN;
}

extern "C" void kernel_launch(void* const* d_in, const int* in_sizes, int n_in,
                              void* d_out, int out_size, void* d_ws, size_t ws_size,
                              hipStream_t stream) {
    const float* features   = (const float*)d_in[0];
    const float* base_point = (const float*)d_in[1];
    const float* adj        = (const float*)d_in[2];
    const float* point_mask = (const float*)d_in[3];
    const float* w_first    = (const float*)d_in[4];
    const float* b_first    = (const float*)d_in[5];
    const float* w_mid      = (const float*)d_in[6];
    const float* b_mid      = (const float*)d_in[7];
    const float* w_last     = (const float*)d_in[8];
    const float* b_last     = (const float*)d_in[9];
    const float* w_fc       = (const float*)d_in[10];
    const float* b_fc       = (const float*)d_in[11];
    float* out = (float*)d_out;
    char* W = (char*)d_ws;

    bf16* adjB   = (bf16*)W;                         // 16.78 MB
    bf16* wT     = (bf16*)(W + 16777216);            // 28 x 128 KB
    bf16* x0p    = (bf16*)(W + 20447232);            // 2 MB each below
    bf16* g1b[2] = { (bf16*)(W + 22544384), (bf16*)(W + 24641536) };
    bf16* g2T    = (bf16*)(W + 26738688);
    bf16* Y0     = (bf16*)(W + 28835840);
    bf16* Y1     = (bf16*)(W + 30932992);
    bf16* xsl[2] = { (bf16*)(W + 33030144), (bf16*)(W + 35127296) };
    bf16* xscr   = (bf16*)(W + 37224448);
    float* dpts  = (float*)(W + 39321600);
    float* tvals = (float*)(W + 39354368);

    prep_kernel<<<9984, 256, 0, stream>>>(adj, adjB, features, base_point, x0p,
                                          w_first, w_mid, w_last, wT);

    dim3 gS(4, 128);
    dim3 gB(4, 32, 4);

    // L0
    s_kernel<<<gS, 256, 0, stream>>>(x0p, nullptr, nullptr, nullptr, nullptr, nullptr, 0,
                                     wT, xscr, g1b[0], g2T);
    adjb_kernel<<<gB, 256, 0, stream>>>(adjB, g2T, Y0, Y1);

    for (int k = 1; k < 14; ++k) {
        const float *bb1, *bb2;
        const bf16* resp = nullptr;
        bf16* xw;
        int rl;
        if (k == 1) {
            bb1 = b_first; bb2 = b_first + 256; rl = 0; xw = xsl[0];
        } else if ((k & 1) == 0) {                      // combine after gcn1 of block m
            int m = (k - 2) / 2;
            bb1 = b_mid + (size_t)m * 1024; bb2 = bb1 + 256;
            rl = 1; xw = xscr;
        } else {                                        // combine after gcn2 of block m: +res, relu
            int m = (k - 3) / 2;
            bb1 = b_mid + (size_t)m * 1024 + 512; bb2 = bb1 + 256;
            rl = 1;
            resp = xsl[((k - 3) / 2) & 1];
            xw   = xsl[((k - 1) / 2) & 1];
        }
        s_kernel<<<gS, 256, 0, stream>>>(g1b[(k - 1) & 1], Y0, Y1, bb1, bb2, resp, rl,
                                         wT + (size_t)2 * k * 65536, xw, g1b[k & 1], g2T);
        adjb_kernel<<<gB, 256, 0, stream>>>(adjB, g2T, Y0, Y1);
    }

    head_kernel<<<16, 256, 0, stream>>>(g1b[1], Y0, Y1, b_last, w_fc, b_fc,
                                        base_point, point_mask, out, dpts);
    lap_rows<<<1024, 256, 0, stream>>>(adjB, dpts, tvals);
    lap_reduce<<<BB, 256, 0, stream>>>(tvals, out + 4 * BB * NN);
}

// Round 4
// 339.922 us; speedup vs baseline: 6.7443x; 1.1079x over previous
//
#include <hip/hip_runtime.h>
#include <hip/hip_bf16.h>
#include <math.h>

#define BB 2
#define NN 2048
#define HH 256
#define WW 256
#define CC 128
#define MIDN 6
#define YSTR 1048576   // elements per Y partial ([4096][256])

typedef __hip_bfloat16 bf16;
typedef short short8 __attribute__((ext_vector_type(8)));
typedef float f32x4 __attribute__((ext_vector_type(4)));
typedef unsigned short ushort4v __attribute__((ext_vector_type(4)));

__device__ inline float bf2f(unsigned short u) {
    return __uint_as_float(((unsigned int)u) << 16);
}
__device__ inline unsigned short f2bf_bits(float f) {
    __hip_bfloat16 h = __float2bfloat16(f);
    return *reinterpret_cast<unsigned short*>(&h);
}

// ======== prep: interleaved {adj f32->bf16 | interp} (0..8191) | weight transpose (8192..9983) ========
__global__ void prep_kernel(const float* __restrict__ adj, bf16* __restrict__ adjB,
                            const float* __restrict__ features, const float* __restrict__ base_point,
                            bf16* __restrict__ x0p,
                            const float* __restrict__ w_first, const float* __restrict__ w_mid,
                            const float* __restrict__ w_last, bf16* __restrict__ wT) {
    __shared__ float tbuf[32][33];
    int bid = blockIdx.x;
    int t = threadIdx.x;
    if (bid < 8192) {
        int sub = bid >> 1;
        if ((bid & 1) == 0) {
            // adj convert: 8 KB per block
            size_t i = ((size_t)sub * 256 + t) * 8;
            float4 f0 = *(const float4*)(adj + i);
            float4 f1 = *(const float4*)(adj + i + 4);
            short8 v;
            v[0] = (short)f2bf_bits(f0.x); v[1] = (short)f2bf_bits(f0.y);
            v[2] = (short)f2bf_bits(f0.z); v[3] = (short)f2bf_bits(f0.w);
            v[4] = (short)f2bf_bits(f1.x); v[5] = (short)f2bf_bits(f1.y);
            v[6] = (short)f2bf_bits(f1.z); v[7] = (short)f2bf_bits(f1.w);
            *(short8*)(adjB + i) = v;
        } else {
            // bilinear interp for point sub
            int idx = sub;
            int b   = idx >> 11;
            float xs = base_point[idx * 2 + 0] * (float)WW;
            float ys = base_point[idx * 2 + 1] * (float)HH;
            float x0f = floorf(xs), y0f = floorf(ys);
            float x1f = x0f + 1.f, y1f = y0f + 1.f;
            float w00 = (x1f - xs) * (y1f - ys);
            float w01 = (x1f - xs) * (ys - y0f);
            float w10 = (xs - x0f) * (y1f - ys);
            float w11 = (xs - x0f) * (ys - y0f);
            int X0 = (int)fminf(fmaxf(x0f, 0.f), (float)(WW - 1));
            int X1 = (int)fminf(fmaxf(x1f, 0.f), (float)(WW - 1));
            int Y0 = (int)fminf(fmaxf(y0f, 0.f), (float)(HH - 1));
            int Y1 = (int)fminf(fmaxf(y1f, 0.f), (float)(HH - 1));
            int p00 = Y0 * WW + X0, p01 = Y1 * WW + X0;
            int p10 = Y0 * WW + X1, p11 = Y1 * WW + X1;
            float val = 0.f;
            if (t < CC) {
                const float* f = features + (size_t)(b * CC + t) * (HH * WW);
                val = w00 * f[p00] + w01 * f[p01] + w10 * f[p10] + w11 * f[p11];
            } else if (t == CC) {
                val = base_point[idx * 2 + 0];
            } else if (t == CC + 1) {
                val = base_point[idx * 2 + 1];
            }
            x0p[(size_t)idx * 256 + t] = __float2bfloat16(val);
        }
    } else {
        int idx = bid - 8192;               // 0..1791
        int m   = idx >> 6;                 // matrix 0..27
        int sub = idx & 63;
        int bx = sub & 7, by = sub >> 3;
        const float* S; int R;
        if (m < 2)       { S = w_first + (size_t)m * 130 * 256; R = 130; }
        else if (m < 26) { S = w_mid + (size_t)(m - 2) * 65536; R = 256; }
        else             { S = w_last + (size_t)(m - 26) * 65536; R = 256; }
        bf16* D = wT + (size_t)m * 65536;
        int tx = t & 31, ty = t >> 5;
        int c0 = bx * 32, r0 = by * 32;
        #pragma unroll
        for (int k = 0; k < 4; ++k) {
            int r = r0 + ty + 8 * k;
            tbuf[ty + 8 * k][tx] = (r < R) ? S[(size_t)r * 256 + c0 + tx] : 0.f;
        }
        __syncthreads();
        #pragma unroll
        for (int k = 0; k < 4; ++k) {
            int c = c0 + ty + 8 * k;
            D[(size_t)c * 256 + r0 + tx] = __float2bfloat16(tbuf[tx][ty + 8 * k]);
        }
    }
}

// ======== S: x = combine(gprev + Y0..Y3 + b1 + b2 [+res][relu]) ; [g1|g2T] = x @ wcat ========
// 512 blocks 1-D (XCD-swizzled): lin = ct(4) + 4*rt(128). 256 threads.
__global__ __launch_bounds__(256) void s_kernel(const bf16* __restrict__ gprev,
                                                const bf16* __restrict__ Yb,
                                                const float* __restrict__ bias1,
                                                const float* __restrict__ bias2,
                                                const bf16* __restrict__ res,
                                                int relu,
                                                const bf16* __restrict__ wcat,
                                                bf16* __restrict__ xR,
                                                bf16* __restrict__ g1out,
                                                bf16* __restrict__ g2T) {
    __shared__ bf16 Al[32 * 64];    // 4 KB, 128B rows, XOR swizzled
    __shared__ bf16 Bl[128 * 64];   // 16 KB
    int tid = threadIdx.x;
    int bid = blockIdx.x;
    int lin = (bid & 7) * 64 + (bid >> 3);
    int ct = lin & 3, rt = lin >> 2;
    int lane = tid & 63, w = tid >> 6;
    int wr = w >> 1, wc = w & 1;       // wave: 16 rows x 64 outfeats
    int row16 = lane & 15, kg = lane >> 4;
    f32x4 acc[4] = {};
    for (int it = 0; it < 4; ++it) {
        // ---- A: combine + swizzled ds_write (one b128/thread) ----
        {
            int d = tid * 16;
            int row = d >> 7;              // 0..31
            int cb = d & 127;
            int gcol = it * 64 + (cb >> 1);
            int ridx = rt * 32 + row;
            size_t off = (size_t)ridx * 256 + gcol;
            short8 gv = *(const short8*)(gprev + off);
            short8 pk;
            if (Yb) {
                float fv[8];
                #pragma unroll
                for (int j = 0; j < 8; ++j) fv[j] = bf2f((unsigned short)gv[j]);
                #pragma unroll
                for (int p = 0; p < 4; ++p) {
                    short8 yv = *(const short8*)(Yb + (size_t)p * YSTR + off);
                    #pragma unroll
                    for (int j = 0; j < 8; ++j) fv[j] += bf2f((unsigned short)yv[j]);
                }
                short8 rv = {};
                if (res) rv = *(const short8*)(res + off);
                #pragma unroll
                for (int j = 0; j < 8; ++j) {
                    float f = fv[j] + bias1[gcol + j] + bias2[gcol + j];
                    if (res)  f += bf2f((unsigned short)rv[j]);
                    if (relu) f = fmaxf(f, 0.f);
                    pk[j] = (short)f2bf_bits(f);
                }
            } else {
                pk = gv;
            }
            if (ct == 0) *(short8*)(xR + off) = pk;
            int byte = row * 128 + (cb ^ ((row & 7) << 4));
            *(short8*)((char*)Al + byte) = pk;
        }
        // ---- B: weights via global_load_lds (pre-swizzled source) ----
        #pragma unroll
        for (int rnd = 0; rnd < 4; ++rnd) {
            int d = tid * 16 + rnd * 4096;
            int row = d >> 7;              // outfeat-in-tile 0..127
            int cb = d & 127;
            int sc = (cb ^ ((row & 7) << 4)) >> 1;
            __builtin_amdgcn_global_load_lds(
                (const __attribute__((address_space(1))) void*)(wcat + (size_t)(ct * 128 + row) * 256 + it * 64 + sc),
                (__attribute__((address_space(3))) void*)((char*)Bl + (w << 10) + rnd * 4096),
                16, 0, 0);
        }
        asm volatile("s_waitcnt vmcnt(0)" ::: "memory");
        __syncthreads();
        #pragma unroll
        for (int kk = 0; kk < 2; ++kk) {
            int arow = wr * 16 + row16;
            int abyte = arow * 128 + (((kk * 64) + kg * 16) ^ ((arow & 7) << 4));
            short8 a = *(const short8*)((const char*)Al + abyte);
            #pragma unroll
            for (int nf = 0; nf < 4; ++nf) {
                int fr = wc * 64 + nf * 16 + row16;
                int byte = fr * 128 + (((kk * 64) + kg * 16) ^ ((fr & 7) << 4));
                short8 bfr = *(const short8*)((const char*)Bl + byte);
                acc[nf] = __builtin_amdgcn_mfma_f32_16x16x32_bf16(a, bfr, acc[nf], 0, 0, 0);
            }
        }
        __syncthreads();
    }
    int cbase = ct * 128 + wc * 64;
    int rb = rt * 32 + wr * 16 + kg * 4;
    if (cbase < 256) {
        #pragma unroll
        for (int nf = 0; nf < 4; ++nf) {
            int c = cbase + nf * 16 + row16;
            #pragma unroll
            for (int j = 0; j < 4; ++j)
                *reinterpret_cast<unsigned short*>(&g1out[(size_t)(rb + j) * 256 + c]) = f2bf_bits(acc[nf][j]);
        }
    } else {
        #pragma unroll
        for (int nf = 0; nf < 4; ++nf) {
            int c = cbase - 256 + nf * 16 + row16;
            ushort4v pk;
            #pragma unroll
            for (int j = 0; j < 4; ++j) pk[j] = f2bf_bits(acc[nf][j]);
            *(ushort4v*)(g2T + (size_t)c * 4096 + rb) = pk;
        }
    }
}

// ======== B: Y[ks] = adj[:, ks quarter] @ g2 — BM=128, BN=64, split-K=4 ========
// 512 blocks 1-D (XCD-swizzled): lin = ct(4) + 4*(rt(16) + 16*z(8)), z = b*4+ks. 256 threads.
__global__ __launch_bounds__(256) void adjb_kernel(const bf16* __restrict__ adjB,
                                                   const bf16* __restrict__ g2T,
                                                   bf16* __restrict__ Ybase) {
    __shared__ bf16 Al[128 * 64];   // 16 KB
    __shared__ bf16 Bl[64 * 64];    // 8 KB
    int tid = threadIdx.x;
    int bid = blockIdx.x;
    int lin = (bid & 7) * 64 + (bid >> 3);
    int ct = lin & 3, rt = (lin >> 2) & 15, z = lin >> 6;
    int b = z >> 2, ks = z & 3;
    const bf16* Aadj = adjB + (size_t)b * NN * NN + (size_t)(rt * 128) * NN + ks * 512;
    const bf16* Bg   = g2T + (size_t)(ct * 64) * 4096 + b * NN + ks * 512;
    bf16* Yo = Ybase + (size_t)ks * YSTR;
    int lane = tid & 63, w = tid >> 6;
    int wr = w >> 1, wc = w & 1;       // wave tile: 64 rows x 32 cols
    int row16 = lane & 15, kg = lane >> 4;
    f32x4 acc[4][2] = {};
    for (int it = 0; it < 8; ++it) {
        int k0 = it * 64;
        #pragma unroll
        for (int rnd = 0; rnd < 4; ++rnd) {
            int d = tid * 16 + rnd * 4096;
            int row = d >> 7, cb = d & 127;     // row 0..127
            int sc = (cb ^ ((row & 7) << 4)) >> 1;
            __builtin_amdgcn_global_load_lds(
                (const __attribute__((address_space(1))) void*)(Aadj + (size_t)row * NN + k0 + sc),
                (__attribute__((address_space(3))) void*)((char*)Al + (w << 10) + rnd * 4096),
                16, 0, 0);
        }
        #pragma unroll
        for (int rnd = 0; rnd < 2; ++rnd) {
            int d = tid * 16 + rnd * 4096;
            int row = d >> 7, cb = d & 127;     // row 0..63 (feature)
            int sc = (cb ^ ((row & 7) << 4)) >> 1;
            __builtin_amdgcn_global_load_lds(
                (const __attribute__((address_space(1))) void*)(Bg + (size_t)row * 4096 + k0 + sc),
                (__attribute__((address_space(3))) void*)((char*)Bl + (w << 10) + rnd * 4096),
                16, 0, 0);
        }
        asm volatile("s_waitcnt vmcnt(0)" ::: "memory");
        __syncthreads();
        #pragma unroll
        for (int kk = 0; kk < 2; ++kk) {
            short8 a[4], bfr[2];
            #pragma unroll
            for (int mf = 0; mf < 4; ++mf) {
                int row = wr * 64 + mf * 16 + row16;
                int byte = row * 128 + (((kk * 64) + kg * 16) ^ ((row & 7) << 4));
                a[mf] = *(const short8*)((const char*)Al + byte);
            }
            #pragma unroll
            for (int nf = 0; nf < 2; ++nf) {
                int fr = wc * 32 + nf * 16 + row16;
                int byte = fr * 128 + (((kk * 64) + kg * 16) ^ ((fr & 7) << 4));
                bfr[nf] = *(const short8*)((const char*)Bl + byte);
            }
            #pragma unroll
            for (int mf = 0; mf < 4; ++mf)
                #pragma unroll
                for (int nf = 0; nf < 2; ++nf)
                    acc[mf][nf] = __builtin_amdgcn_mfma_f32_16x16x32_bf16(a[mf], bfr[nf], acc[mf][nf], 0, 0, 0);
        }
        __syncthreads();
    }
    #pragma unroll
    for (int mf = 0; mf < 4; ++mf) {
        #pragma unroll
        for (int nf = 0; nf < 2; ++nf) {
            int c  = ct * 64 + wc * 32 + nf * 16 + row16;
            int r0 = b * NN + rt * 128 + wr * 64 + mf * 16 + kg * 4;
            #pragma unroll
            for (int j = 0; j < 4; ++j)
                *reinterpret_cast<unsigned short*>(&Yo[(size_t)(r0 + j) * 256 + c]) = f2bf_bits(acc[mf][nf][j]);
        }
    }
}

// ======== head: z = g1 + ΣY + b_last ; gcn_pred = z@w_fc + b_fc ; outputs ========
__global__ void head_kernel(const bf16* __restrict__ g1, const bf16* __restrict__ Yb,
                            const float* __restrict__ b_last,
                            const float* __restrict__ w_fc, const float* __restrict__ b_fc,
                            const float* __restrict__ base_point, const float* __restrict__ point_mask,
                            float* __restrict__ out, float* __restrict__ dpts) {
    int row = blockIdx.x * 256 + threadIdx.x;
    float s0 = b_fc[0], s1 = b_fc[1];
    for (int d = 0; d < 256; d += 8) {
        size_t off = (size_t)row * 256 + d;
        short8 a = *(const short8*)(g1 + off);
        float zv[8];
        #pragma unroll
        for (int j = 0; j < 8; ++j) zv[j] = bf2f((unsigned short)a[j]);
        #pragma unroll
        for (int p = 0; p < 4; ++p) {
            short8 yv = *(const short8*)(Yb + (size_t)p * YSTR + off);
            #pragma unroll
            for (int j = 0; j < 8; ++j) zv[j] += bf2f((unsigned short)yv[j]);
        }
        #pragma unroll
        for (int j = 0; j < 8; ++j) {
            float z = zv[j] + b_last[d + j] + b_last[256 + d + j];
            s0 += z * w_fc[(d + j) * 2 + 0];
            s1 += z * w_fc[(d + j) * 2 + 1];
        }
    }
    float m  = point_mask[row];
    float p0 = base_point[row * 2 + 0] + s0 * m;
    float p1 = base_point[row * 2 + 1] + s1 * m;
    out[row * 2 + 0] = p0;
    out[row * 2 + 1] = p1;
    out[2 * BB * NN + row * 2 + 0] = s0;
    out[2 * BB * NN + row * 2 + 1] = s1;
    dpts[row * 2 + 0] = s0 * m;
    dpts[row * 2 + 1] = s1 * m;
}

// ======== lap ========
__global__ void lap_rows(const bf16* __restrict__ adjB, const float* __restrict__ dpts,
                         float* __restrict__ tvals) {
    int w    = threadIdx.x >> 6;
    int lane = threadIdx.x & 63;
    int row  = blockIdx.x * 4 + w;
    int b = row >> 11, n = row & 2047;
    const bf16* ar = adjB + (size_t)b * NN * NN + (size_t)n * NN;
    const float* db = dpts + (size_t)b * NN * 2;
    float s0 = 0.f, s1 = 0.f;
    for (int k4 = 0; k4 < 4; ++k4) {
        int k = k4 * 512 + lane * 8;
        short8 av = *(const short8*)(ar + k);
        #pragma unroll
        for (int j = 0; j < 8; ++j) {
            float a = bf2f((unsigned short)av[j]);
            float2 dv = *(const float2*)(db + (k + j) * 2);
            s0 += a * dv.x;
            s1 += a * dv.y;
        }
    }
    for (int off = 32; off; off >>= 1) {
        s0 += __shfl_xor(s0, off);
        s1 += __shfl_xor(s1, off);
    }
    if (lane == 0) {
        float e0 = dpts[(size_t)row * 2 + 0] - s0;
        float e1 = dpts[(size_t)row * 2 + 1] - s1;
        tvals[row] = sqrtf(e0 * e0 + e1 * e1 + 1e-10f);
    }
}

__global__ void lap_reduce(const float* __restrict__ tvals, float* __restrict__ outp) {
    __shared__ float sd[256];
    int b = blockIdx.x;
    float s = 0.f;
    for (int i = threadIdx.x; i < NN; i += 256) s += tvals[b * NN + i];
    sd[threadIdx.x] = s;
    __syncthreads();
    for (int o = 128; o; o >>= 1) {
        if (threadIdx.x < o) sd[threadIdx.x] += sd[threadIdx.x + o];
        __syncthreads();
    }
    if (threadIdx.x == 0) outp[b] = sd[0] / (float)NN;
}

extern "C" void kernel_launch(void* const* d_in, const int* in_sizes, int n_in,
                              void* d_out, int out_size, void* d_ws, size_t ws_size,
                              hipStream_t stream) {
    const float* features   = (const float*)d_in[0];
    const float* base_point = (const float*)d_in[1];
    const float* adj        = (const float*)d_in[2];
    const float* point_mask = (const float*)d_in[3];
    const float* w_first    = (const float*)d_in[4];
    const float* b_first    = (const float*)d_in[5];
    const float* w_mid      = (const float*)d_in[6];
    const float* b_mid      = (const float*)d_in[7];
    const float* w_last     = (const float*)d_in[8];
    const float* b_last     = (const float*)d_in[9];
    const float* w_fc       = (const float*)d_in[10];
    const float* b_fc       = (const float*)d_in[11];
    float* out = (float*)d_out;
    char* W = (char*)d_ws;

    bf16* adjB   = (bf16*)W;                          // 16.78 MB
    bf16* wT     = (bf16*)(W + 16777216);             // 3.67 MB
    bf16* x0p    = (bf16*)(W + 20447232);
    bf16* g1b[2] = { (bf16*)(W + 22544384), (bf16*)(W + 24641536) };
    bf16* g2T    = (bf16*)(W + 26738688);
    bf16* Yb     = (bf16*)(W + 28835840);             // 4 partials x 2 MB
    bf16* xsl[2] = { (bf16*)(W + 37224448), (bf16*)(W + 39321600) };
    bf16* xscr   = (bf16*)(W + 41418752);
    float* dpts  = (float*)(W + 43515904);
    float* tvals = (float*)(W + 43548672);

    prep_kernel<<<9984, 256, 0, stream>>>(adj, adjB, features, base_point, x0p,
                                          w_first, w_mid, w_last, wT);

    // L0
    s_kernel<<<512, 256, 0, stream>>>(x0p, nullptr, nullptr, nullptr, nullptr, 0,
                                      wT, xscr, g1b[0], g2T);
    adjb_kernel<<<512, 256, 0, stream>>>(adjB, g2T, Yb);

    for (int k = 1; k < 14; ++k) {
        const float *bb1, *bb2;
        const bf16* resp = nullptr;
        bf16* xw;
        int rl;
        if (k == 1) {
            bb1 = b_first; bb2 = b_first + 256; rl = 0; xw = xsl[0];
        } else if ((k & 1) == 0) {
            int m = (k - 2) / 2;
            bb1 = b_mid + (size_t)m * 1024; bb2 = bb1 + 256;
            rl = 1; xw = xscr;
        } else {
            int m = (k - 3) / 2;
            bb1 = b_mid + (size_t)m * 1024 + 512; bb2 = bb1 + 256;
            rl = 1;
            resp = xsl[m & 1];
            xw   = xsl[((k - 1) / 2) & 1];
        }
        s_kernel<<<512, 256, 0, stream>>>(g1b[(k - 1) & 1], Yb, bb1, bb2, resp, rl,
                                          wT + (size_t)2 * k * 65536, xw, g1b[k & 1], g2T);
        adjb_kernel<<<512, 256, 0, stream>>>(adjB, g2T, Yb);
    }

    head_kernel<<<16, 256, 0, stream>>>(g1b[1], Yb, b_last, w_fc, b_fc,
                                        base_point, point_mask, out, dpts);
    lap_rows<<<1024, 256, 0, stream>>>(adjB, dpts, tvals);
    lap_reduce<<<BB, 256, 0, stream>>>(tvals, out + 4 * BB * NN);
}

// Round 5
// 333.097 us; speedup vs baseline: 6.8826x; 1.0205x over previous
//
#include <hip/hip_runtime.h>
#include <hip/hip_bf16.h>
#include <math.h>

#define BB 2
#define NN 2048
#define HH 256
#define WW 256
#define CC 128
#define MIDN 6
#define YSTR 1048576   // elements per Y partial ([4096][256])

typedef __hip_bfloat16 bf16;
typedef short short8 __attribute__((ext_vector_type(8)));
typedef float f32x4 __attribute__((ext_vector_type(4)));
typedef unsigned short ushort4v __attribute__((ext_vector_type(4)));

__device__ inline float bf2f(unsigned short u) {
    return __uint_as_float(((unsigned int)u) << 16);
}
__device__ inline unsigned short f2bf_bits(float f) {
    __hip_bfloat16 h = __float2bfloat16(f);
    return *reinterpret_cast<unsigned short*>(&h);
}

// ======== prep: interp wave/point (0..1023) | adj f32->bf16 (1024..3071) | weight T (3072..4863) ========
__global__ void prep_kernel(const float* __restrict__ adj, bf16* __restrict__ adjB,
                            const float* __restrict__ features, const float* __restrict__ base_point,
                            bf16* __restrict__ x0p,
                            const float* __restrict__ w_first, const float* __restrict__ w_mid,
                            const float* __restrict__ w_last, bf16* __restrict__ wT) {
    __shared__ float tbuf[32][33];
    int bid = blockIdx.x;
    int t = threadIdx.x;
    if (bid < 1024) {
        // one wave per point, 2 channels per lane
        int wv = t >> 6, lane = t & 63;
        int idx = bid * 4 + wv;             // 0..4095
        int b   = idx >> 11;
        float bx = base_point[idx * 2 + 0];
        float by = base_point[idx * 2 + 1];
        float xs = bx * (float)WW;
        float ys = by * (float)HH;
        float x0f = floorf(xs), y0f = floorf(ys);
        float x1f = x0f + 1.f, y1f = y0f + 1.f;
        float w00 = (x1f - xs) * (y1f - ys);
        float w01 = (x1f - xs) * (ys - y0f);
        float w10 = (xs - x0f) * (y1f - ys);
        float w11 = (xs - x0f) * (ys - y0f);
        int X0 = (int)fminf(fmaxf(x0f, 0.f), (float)(WW - 1));
        int X1 = (int)fminf(fmaxf(x1f, 0.f), (float)(WW - 1));
        int Y0 = (int)fminf(fmaxf(y0f, 0.f), (float)(HH - 1));
        int Y1 = (int)fminf(fmaxf(y1f, 0.f), (float)(HH - 1));
        int p00 = Y0 * WW + X0, p01 = Y1 * WW + X0;
        int p10 = Y0 * WW + X1, p11 = Y1 * WW + X1;
        int c0 = lane * 2;
        const float* f0 = features + (size_t)(b * CC + c0) * (HH * WW);
        const float* f1 = f0 + HH * WW;
        float v0 = w00 * f0[p00] + w01 * f0[p01] + w10 * f0[p10] + w11 * f0[p11];
        float v1 = w00 * f1[p00] + w01 * f1[p01] + w10 * f1[p10] + w11 * f1[p11];
        unsigned int pk = (unsigned int)f2bf_bits(v0) | ((unsigned int)f2bf_bits(v1) << 16);
        *(unsigned int*)(x0p + (size_t)idx * 256 + c0) = pk;
        // cols 128..255: (bx,by) then zeros
        unsigned int pk2 = 0;
        if (lane == 0)
            pk2 = (unsigned int)f2bf_bits(bx) | ((unsigned int)f2bf_bits(by) << 16);
        *(unsigned int*)(x0p + (size_t)idx * 256 + 128 + c0) = pk2;
    } else if (bid < 3072) {
        int sub = bid - 1024;
        size_t i = ((size_t)sub * 4096) + (size_t)t * 16;
        #pragma unroll
        for (int h = 0; h < 2; ++h) {
            float4 f0 = *(const float4*)(adj + i + h * 8);
            float4 f1 = *(const float4*)(adj + i + h * 8 + 4);
            short8 v;
            v[0] = (short)f2bf_bits(f0.x); v[1] = (short)f2bf_bits(f0.y);
            v[2] = (short)f2bf_bits(f0.z); v[3] = (short)f2bf_bits(f0.w);
            v[4] = (short)f2bf_bits(f1.x); v[5] = (short)f2bf_bits(f1.y);
            v[6] = (short)f2bf_bits(f1.z); v[7] = (short)f2bf_bits(f1.w);
            *(short8*)(adjB + i + h * 8) = v;
        }
    } else {
        int idx = bid - 3072;               // 0..1791
        int m   = idx >> 6;                 // matrix 0..27
        int sub = idx & 63;
        int bx = sub & 7, by = sub >> 3;
        const float* S; int R;
        if (m < 2)       { S = w_first + (size_t)m * 130 * 256; R = 130; }
        else if (m < 26) { S = w_mid + (size_t)(m - 2) * 65536; R = 256; }
        else             { S = w_last + (size_t)(m - 26) * 65536; R = 256; }
        bf16* D = wT + (size_t)m * 65536;
        int tx = t & 31, ty = t >> 5;
        int c0 = bx * 32, r0 = by * 32;
        #pragma unroll
        for (int k = 0; k < 4; ++k) {
            int r = r0 + ty + 8 * k;
            tbuf[ty + 8 * k][tx] = (r < R) ? S[(size_t)r * 256 + c0 + tx] : 0.f;
        }
        __syncthreads();
        #pragma unroll
        for (int k = 0; k < 4; ++k) {
            int c = c0 + ty + 8 * k;
            D[(size_t)c * 256 + r0 + tx] = __float2bfloat16(tbuf[tx][ty + 8 * k]);
        }
    }
}

// ======== S: x = combine(gprev + Y0..Y3 + b1 + b2 [+res][relu]) ; [g1|g2T] = x @ wcat ========
// 512 blocks 1-D (XCD-swizzled): lin = ct(4) + 4*rt(128). 256 threads. 2-phase pipelined.
__global__ __launch_bounds__(256) void s_kernel(const bf16* __restrict__ gprev,
                                                const bf16* __restrict__ Yb,
                                                const float* __restrict__ bias1,
                                                const float* __restrict__ bias2,
                                                const bf16* __restrict__ res,
                                                int relu,
                                                const bf16* __restrict__ wcat,
                                                bf16* __restrict__ xR,
                                                bf16* __restrict__ g1out,
                                                bf16* __restrict__ g2T) {
    __shared__ bf16 Al[2 * 32 * 64];    // 2 x 4 KB, 128B rows, XOR swizzled
    __shared__ bf16 Bl[2 * 128 * 64];   // 2 x 16 KB
    int tid = threadIdx.x;
    int bid = blockIdx.x;
    int lin = (bid & 7) * 64 + (bid >> 3);
    int ct = lin & 3, rt = lin >> 2;
    int lane = tid & 63, w = tid >> 6;
    int wr = w >> 1, wc = w & 1;       // wave: 16 rows x 64 outfeats
    int row16 = lane & 15, kg = lane >> 4;

    // per-thread A-combine geometry (constant across iterations)
    int ad  = tid * 16;
    int arw = ad >> 7;                 // 0..31
    int acb = ad & 127;
    int ridx = rt * 32 + arw;
    int awbyte = arw * 128 + (acb ^ ((arw & 7) << 4));   // swizzled ds_write byte off
    int gc_base = acb >> 1;            // column base within 64-group

    #define STAGE_B(buf, it)                                                              \
        _Pragma("unroll")                                                                 \
        for (int rnd = 0; rnd < 4; ++rnd) {                                               \
            int d = tid * 16 + rnd * 4096;                                                \
            int row = d >> 7;                                                             \
            int cb = d & 127;                                                             \
            int sc = (cb ^ ((row & 7) << 4)) >> 1;                                        \
            __builtin_amdgcn_global_load_lds(                                             \
                (const __attribute__((address_space(1))) void*)(wcat + (size_t)(ct * 128 + row) * 256 + (it) * 64 + sc), \
                (__attribute__((address_space(3))) void*)((char*)Bl + (buf) * 16384 + (w << 10) + rnd * 4096), \
                16, 0, 0);                                                                \
        }

    // combine loads for iteration it -> registers
    short8 gv, yv0, yv1, yv2, yv3, rv;
    #define LOADS_A(it)                                                                   \
        {                                                                                 \
            size_t off = (size_t)ridx * 256 + (it) * 64 + gc_base;                        \
            gv = *(const short8*)(gprev + off);                                           \
            if (Yb) {                                                                     \
                yv0 = *(const short8*)(Yb + off);                                         \
                yv1 = *(const short8*)(Yb + YSTR + off);                                  \
                yv2 = *(const short8*)(Yb + 2 * YSTR + off);                              \
                yv3 = *(const short8*)(Yb + 3 * YSTR + off);                              \
                if (res) rv = *(const short8*)(res + off);                                \
            }                                                                             \
        }

    #define COMBINE_WRITE_A(buf, it)                                                     \
        {                                                                                 \
            int gcol = (it) * 64 + gc_base;                                               \
            short8 pk;                                                                    \
            if (Yb) {                                                                     \
                _Pragma("unroll")                                                         \
                for (int j = 0; j < 8; ++j) {                                             \
                    float f = bf2f((unsigned short)gv[j]) + bf2f((unsigned short)yv0[j])  \
                            + bf2f((unsigned short)yv1[j]) + bf2f((unsigned short)yv2[j]) \
                            + bf2f((unsigned short)yv3[j])                                \
                            + bias1[gcol + j] + bias2[gcol + j];                          \
                    if (res)  f += bf2f((unsigned short)rv[j]);                           \
                    if (relu) f = fmaxf(f, 0.f);                                          \
                    pk[j] = (short)f2bf_bits(f);                                          \
                }                                                                         \
            } else {                                                                      \
                pk = gv;                                                                  \
            }                                                                             \
            if (ct == 0) *(short8*)(xR + (size_t)ridx * 256 + gcol) = pk;                 \
            *(short8*)((char*)Al + (buf) * 4096 + awbyte) = pk;                           \
        }

    f32x4 acc[4] = {};

    // prologue
    STAGE_B(0, 0);
    LOADS_A(0);
    COMBINE_WRITE_A(0, 0);
    asm volatile("s_waitcnt vmcnt(0) lgkmcnt(0)" ::: "memory");
    __builtin_amdgcn_s_barrier();

    #pragma unroll
    for (int it = 0; it < 4; ++it) {
        int cur = it & 1;
        if (it < 3) {
            STAGE_B(cur ^ 1, it + 1);
            LOADS_A(it + 1);
        }
        // MFMA from buffers [cur]
        #pragma unroll
        for (int kk = 0; kk < 2; ++kk) {
            int arow = wr * 16 + row16;
            int abyte = cur * 4096 + arow * 128 + (((kk * 64) + kg * 16) ^ ((arow & 7) << 4));
            short8 a = *(const short8*)((const char*)Al + abyte);
            #pragma unroll
            for (int nf = 0; nf < 4; ++nf) {
                int fr = wc * 64 + nf * 16 + row16;
                int byte = cur * 16384 + fr * 128 + (((kk * 64) + kg * 16) ^ ((fr & 7) << 4));
                short8 bfr = *(const short8*)((const char*)Bl + byte);
                acc[nf] = __builtin_amdgcn_mfma_f32_16x16x32_bf16(a, bfr, acc[nf], 0, 0, 0);
            }
        }
        if (it < 3) {
            COMBINE_WRITE_A(cur ^ 1, it + 1);
            asm volatile("s_waitcnt vmcnt(0) lgkmcnt(0)" ::: "memory");
            __builtin_amdgcn_s_barrier();
        }
    }

    int cbase = ct * 128 + wc * 64;
    int rb = rt * 32 + wr * 16 + kg * 4;
    if (cbase < 256) {
        #pragma unroll
        for (int nf = 0; nf < 4; ++nf) {
            int c = cbase + nf * 16 + row16;
            #pragma unroll
            for (int j = 0; j < 4; ++j)
                *reinterpret_cast<unsigned short*>(&g1out[(size_t)(rb + j) * 256 + c]) = f2bf_bits(acc[nf][j]);
        }
    } else {
        #pragma unroll
        for (int nf = 0; nf < 4; ++nf) {
            int c = cbase - 256 + nf * 16 + row16;
            ushort4v pk;
            #pragma unroll
            for (int j = 0; j < 4; ++j) pk[j] = f2bf_bits(acc[nf][j]);
            *(ushort4v*)(g2T + (size_t)c * 4096 + rb) = pk;
        }
    }
    #undef STAGE_B
    #undef LOADS_A
    #undef COMBINE_WRITE_A
}

// ======== B: Y[ks] = adj[:, ks quarter] @ g2 — BM=128, BN=64, split-K=4, 2-phase pipelined ========
// 512 blocks 1-D (XCD-swizzled): lin = ct(4) + 4*(rt(16) + 16*z(8)), z = b*4+ks. 256 threads.
__global__ __launch_bounds__(256) void adjb_kernel(const bf16* __restrict__ adjB,
                                                   const bf16* __restrict__ g2T,
                                                   bf16* __restrict__ Ybase) {
    __shared__ bf16 Al[2 * 128 * 64];   // 2 x 16 KB
    __shared__ bf16 Bl[2 * 64 * 64];    // 2 x 8 KB
    int tid = threadIdx.x;
    int bid = blockIdx.x;
    int lin = (bid & 7) * 64 + (bid >> 3);
    int ct = lin & 3, rt = (lin >> 2) & 15, z = lin >> 6;
    int b = z >> 2, ks = z & 3;
    const bf16* Aadj = adjB + (size_t)b * NN * NN + (size_t)(rt * 128) * NN + ks * 512;
    const bf16* Bg   = g2T + (size_t)(ct * 64) * 4096 + b * NN + ks * 512;
    bf16* Yo = Ybase + (size_t)ks * YSTR;
    int lane = tid & 63, w = tid >> 6;
    int wr = w >> 1, wc = w & 1;       // wave tile: 64 rows x 32 cols
    int row16 = lane & 15, kg = lane >> 4;

    #define STAGE(buf, it)                                                                \
        {                                                                                 \
            int k0 = (it) * 64;                                                           \
            _Pragma("unroll")                                                             \
            for (int rnd = 0; rnd < 4; ++rnd) {                                           \
                int d = tid * 16 + rnd * 4096;                                            \
                int row = d >> 7, cb = d & 127;                                           \
                int sc = (cb ^ ((row & 7) << 4)) >> 1;                                    \
                __builtin_amdgcn_global_load_lds(                                         \
                    (const __attribute__((address_space(1))) void*)(Aadj + (size_t)row * NN + k0 + sc), \
                    (__attribute__((address_space(3))) void*)((char*)Al + (buf) * 16384 + (w << 10) + rnd * 4096), \
                    16, 0, 0);                                                            \
            }                                                                             \
            _Pragma("unroll")                                                             \
            for (int rnd = 0; rnd < 2; ++rnd) {                                           \
                int d = tid * 16 + rnd * 4096;                                            \
                int row = d >> 7, cb = d & 127;                                           \
                int sc = (cb ^ ((row & 7) << 4)) >> 1;                                    \
                __builtin_amdgcn_global_load_lds(                                         \
                    (const __attribute__((address_space(1))) void*)(Bg + (size_t)row * 4096 + k0 + sc), \
                    (__attribute__((address_space(3))) void*)((char*)Bl + (buf) * 8192 + (w << 10) + rnd * 4096), \
                    16, 0, 0);                                                            \
            }                                                                             \
        }

    f32x4 acc[4][2] = {};

    STAGE(0, 0);
    asm volatile("s_waitcnt vmcnt(0)" ::: "memory");
    __builtin_amdgcn_s_barrier();

    #pragma unroll 1
    for (int it = 0; it < 8; ++it) {
        int cur = it & 1;
        if (it < 7) STAGE(cur ^ 1, it + 1);
        #pragma unroll
        for (int kk = 0; kk < 2; ++kk) {
            short8 a[4], bfr[2];
            #pragma unroll
            for (int mf = 0; mf < 4; ++mf) {
                int row = wr * 64 + mf * 16 + row16;
                int byte = cur * 16384 + row * 128 + (((kk * 64) + kg * 16) ^ ((row & 7) << 4));
                a[mf] = *(const short8*)((const char*)Al + byte);
            }
            #pragma unroll
            for (int nf = 0; nf < 2; ++nf) {
                int fr = wc * 32 + nf * 16 + row16;
                int byte = cur * 8192 + fr * 128 + (((kk * 64) + kg * 16) ^ ((fr & 7) << 4));
                bfr[nf] = *(const short8*)((const char*)Bl + byte);
            }
            #pragma unroll
            for (int mf = 0; mf < 4; ++mf)
                #pragma unroll
                for (int nf = 0; nf < 2; ++nf)
                    acc[mf][nf] = __builtin_amdgcn_mfma_f32_16x16x32_bf16(a[mf], bfr[nf], acc[mf][nf], 0, 0, 0);
        }
        asm volatile("s_waitcnt vmcnt(0)" ::: "memory");
        __builtin_amdgcn_s_barrier();
    }

    #pragma unroll
    for (int mf = 0; mf < 4; ++mf) {
        #pragma unroll
        for (int nf = 0; nf < 2; ++nf) {
            int c  = ct * 64 + wc * 32 + nf * 16 + row16;
            int r0 = b * NN + rt * 128 + wr * 64 + mf * 16 + kg * 4;
            #pragma unroll
            for (int j = 0; j < 4; ++j)
                *reinterpret_cast<unsigned short*>(&Yo[(size_t)(r0 + j) * 256 + c]) = f2bf_bits(acc[mf][nf][j]);
        }
    }
    #undef STAGE
}

// ======== head: z = g1 + ΣY + b_last ; gcn_pred = z@w_fc + b_fc ; outputs ========
__global__ void head_kernel(const bf16* __restrict__ g1, const bf16* __restrict__ Yb,
                            const float* __restrict__ b_last,
                            const float* __restrict__ w_fc, const float* __restrict__ b_fc,
                            const float* __restrict__ base_point, const float* __restrict__ point_mask,
                            float* __restrict__ out, float* __restrict__ dpts) {
    int row = blockIdx.x * 256 + threadIdx.x;
    float s0 = b_fc[0], s1 = b_fc[1];
    for (int d = 0; d < 256; d += 8) {
        size_t off = (size_t)row * 256 + d;
        short8 a = *(const short8*)(g1 + off);
        float zv[8];
        #pragma unroll
        for (int j = 0; j < 8; ++j) zv[j] = bf2f((unsigned short)a[j]);
        #pragma unroll
        for (int p = 0; p < 4; ++p) {
            short8 yv = *(const short8*)(Yb + (size_t)p * YSTR + off);
            #pragma unroll
            for (int j = 0; j < 8; ++j) zv[j] += bf2f((unsigned short)yv[j]);
        }
        #pragma unroll
        for (int j = 0; j < 8; ++j) {
            float z = zv[j] + b_last[d + j] + b_last[256 + d + j];
            s0 += z * w_fc[(d + j) * 2 + 0];
            s1 += z * w_fc[(d + j) * 2 + 1];
        }
    }
    float m  = point_mask[row];
    float p0 = base_point[row * 2 + 0] + s0 * m;
    float p1 = base_point[row * 2 + 1] + s1 * m;
    out[row * 2 + 0] = p0;
    out[row * 2 + 1] = p1;
    out[2 * BB * NN + row * 2 + 0] = s0;
    out[2 * BB * NN + row * 2 + 1] = s1;
    dpts[row * 2 + 0] = s0 * m;
    dpts[row * 2 + 1] = s1 * m;
}

// ======== lap ========
__global__ void lap_rows(const bf16* __restrict__ adjB, const float* __restrict__ dpts,
                         float* __restrict__ tvals) {
    int w    = threadIdx.x >> 6;
    int lane = threadIdx.x & 63;
    int row  = blockIdx.x * 4 + w;
    int b = row >> 11, n = row & 2047;
    const bf16* ar = adjB + (size_t)b * NN * NN + (size_t)n * NN;
    const float* db = dpts + (size_t)b * NN * 2;
    float s0 = 0.f, s1 = 0.f;
    for (int k4 = 0; k4 < 4; ++k4) {
        int k = k4 * 512 + lane * 8;
        short8 av = *(const short8*)(ar + k);
        #pragma unroll
        for (int j = 0; j < 8; ++j) {
            float a = bf2f((unsigned short)av[j]);
            float2 dv = *(const float2*)(db + (k + j) * 2);
            s0 += a * dv.x;
            s1 += a * dv.y;
        }
    }
    for (int off = 32; off; off >>= 1) {
        s0 += __shfl_xor(s0, off);
        s1 += __shfl_xor(s1, off);
    }
    if (lane == 0) {
        float e0 = dpts[(size_t)row * 2 + 0] - s0;
        float e1 = dpts[(size_t)row * 2 + 1] - s1;
        tvals[row] = sqrtf(e0 * e0 + e1 * e1 + 1e-10f);
    }
}

__global__ void lap_reduce(const float* __restrict__ tvals, float* __restrict__ outp) {
    __shared__ float sd[256];
    int b = blockIdx.x;
    float s = 0.f;
    for (int i = threadIdx.x; i < NN; i += 256) s += tvals[b * NN + i];
    sd[threadIdx.x] = s;
    __syncthreads();
    for (int o = 128; o; o >>= 1) {
        if (threadIdx.x < o) sd[threadIdx.x] += sd[threadIdx.x + o];
        __syncthreads();
    }
    if (threadIdx.x == 0) outp[b] = sd[0] / (float)NN;
}

extern "C" void kernel_launch(void* const* d_in, const int* in_sizes, int n_in,
                              void* d_out, int out_size, void* d_ws, size_t ws_size,
                              hipStream_t stream) {
    const float* features   = (const float*)d_in[0];
    const float* base_point = (const float*)d_in[1];
    const float* adj        = (const float*)d_in[2];
    const float* point_mask = (const float*)d_in[3];
    const float* w_first    = (const float*)d_in[4];
    const float* b_first    = (const float*)d_in[5];
    const float* w_mid      = (const float*)d_in[6];
    const float* b_mid      = (const float*)d_in[7];
    const float* w_last     = (const float*)d_in[8];
    const float* b_last     = (const float*)d_in[9];
    const float* w_fc       = (const float*)d_in[10];
    const float* b_fc       = (const float*)d_in[11];
    float* out = (float*)d_out;
    char* W = (char*)d_ws;

    bf16* adjB   = (bf16*)W;                          // 16.78 MB
    bf16* wT     = (bf16*)(W + 16777216);             // 3.67 MB
    bf16* x0p    = (bf16*)(W + 20447232);
    bf16* g1b[2] = { (bf16*)(W + 22544384), (bf16*)(W + 24641536) };
    bf16* g2T    = (bf16*)(W + 26738688);
    bf16* Yb     = (bf16*)(W + 28835840);             // 4 partials x 2 MB
    bf16* xsl[2] = { (bf16*)(W + 37224448), (bf16*)(W + 39321600) };
    bf16* xscr   = (bf16*)(W + 41418752);
    float* dpts  = (float*)(W + 43515904);
    float* tvals = (float*)(W + 43548672);

    prep_kernel<<<4864, 256, 0, stream>>>(adj, adjB, features, base_point, x0p,
                                          w_first, w_mid, w_last, wT);

    // L0
    s_kernel<<<512, 256, 0, stream>>>(x0p, nullptr, nullptr, nullptr, nullptr, 0,
                                      wT, xscr, g1b[0], g2T);
    adjb_kernel<<<512, 256, 0, stream>>>(adjB, g2T, Yb);

    for (int k = 1; k < 14; ++k) {
        const float *bb1, *bb2;
        const bf16* resp = nullptr;
        bf16* xw;
        int rl;
        if (k == 1) {
            bb1 = b_first; bb2 = b_first + 256; rl = 0; xw = xsl[0];
        } else if ((k & 1) == 0) {
            int m = (k - 2) / 2;
            bb1 = b_mid + (size_t)m * 1024; bb2 = bb1 + 256;
            rl = 1; xw = xscr;
        } else {
            int m = (k - 3) / 2;
            bb1 = b_mid + (size_t)m * 1024 + 512; bb2 = bb1 + 256;
            rl = 1;
            resp = xsl[m & 1];
            xw   = xsl[((k - 1) / 2) & 1];
        }
        s_kernel<<<512, 256, 0, stream>>>(g1b[(k - 1) & 1], Yb, bb1, bb2, resp, rl,
                                          wT + (size_t)2 * k * 65536, xw, g1b[k & 1], g2T);
        adjb_kernel<<<512, 256, 0, stream>>>(adjB, g2T, Yb);
    }

    head_kernel<<<16, 256, 0, stream>>>(g1b[1], Yb, b_last, w_fc, b_fc,
                                        base_point, point_mask, out, dpts);
    lap_rows<<<1024, 256, 0, stream>>>(adjB, dpts, tvals);
    lap_reduce<<<BB, 256, 0, stream>>>(tvals, out + 4 * BB * NN);
}

// Round 6
// 324.644 us; speedup vs baseline: 7.0618x; 1.0260x over previous
//
#include <hip/hip_runtime.h>
#include <hip/hip_bf16.h>
#include <math.h>

#define BB 2
#define NN 2048
#define HH 256
#define WW 256
#define CC 128
#define MIDN 6
#define YSTR 1048576   // elements per Y partial ([4096][256])

typedef __hip_bfloat16 bf16;
typedef short short8 __attribute__((ext_vector_type(8)));
typedef float f32x4 __attribute__((ext_vector_type(4)));
typedef unsigned short ushort4v __attribute__((ext_vector_type(4)));

__device__ inline float bf2f(unsigned short u) {
    return __uint_as_float(((unsigned int)u) << 16);
}
__device__ inline unsigned short f2bf_bits(float f) {
    __hip_bfloat16 h = __float2bfloat16(f);
    return *reinterpret_cast<unsigned short*>(&h);
}

// ======== prep: interp (0..1023) | adj f32->bf16 (1024..2047) | weight T (2048..3839) ========
__global__ void prep_kernel(const float* __restrict__ adj, bf16* __restrict__ adjB,
                            const float* __restrict__ features, const float* __restrict__ base_point,
                            bf16* __restrict__ x0p,
                            const float* __restrict__ w_first, const float* __restrict__ w_mid,
                            const float* __restrict__ w_last, bf16* __restrict__ wT) {
    __shared__ float tbuf[32][33];
    int bid = blockIdx.x;
    int t = threadIdx.x;
    if (bid < 1024) {
        // one wave per point, 2 channels per lane
        int wv = t >> 6, lane = t & 63;
        int idx = bid * 4 + wv;             // 0..4095
        int b   = idx >> 11;
        float bx = base_point[idx * 2 + 0];
        float by = base_point[idx * 2 + 1];
        float xs = bx * (float)WW;
        float ys = by * (float)HH;
        float x0f = floorf(xs), y0f = floorf(ys);
        float x1f = x0f + 1.f, y1f = y0f + 1.f;
        float w00 = (x1f - xs) * (y1f - ys);
        float w01 = (x1f - xs) * (ys - y0f);
        float w10 = (xs - x0f) * (y1f - ys);
        float w11 = (xs - x0f) * (ys - y0f);
        int X0 = (int)fminf(fmaxf(x0f, 0.f), (float)(WW - 1));
        int X1 = (int)fminf(fmaxf(x1f, 0.f), (float)(WW - 1));
        int Y0 = (int)fminf(fmaxf(y0f, 0.f), (float)(HH - 1));
        int Y1 = (int)fminf(fmaxf(y1f, 0.f), (float)(HH - 1));
        int p00 = Y0 * WW + X0, p01 = Y1 * WW + X0;
        int p10 = Y0 * WW + X1, p11 = Y1 * WW + X1;
        int c0 = lane * 2;
        const float* f0 = features + (size_t)(b * CC + c0) * (HH * WW);
        const float* f1 = f0 + HH * WW;
        float v0 = w00 * f0[p00] + w01 * f0[p01] + w10 * f0[p10] + w11 * f0[p11];
        float v1 = w00 * f1[p00] + w01 * f1[p01] + w10 * f1[p10] + w11 * f1[p11];
        unsigned int pk = (unsigned int)f2bf_bits(v0) | ((unsigned int)f2bf_bits(v1) << 16);
        *(unsigned int*)(x0p + (size_t)idx * 256 + c0) = pk;
        unsigned int pk2 = 0;
        if (lane == 0)
            pk2 = (unsigned int)f2bf_bits(bx) | ((unsigned int)f2bf_bits(by) << 16);
        *(unsigned int*)(x0p + (size_t)idx * 256 + 128 + c0) = pk2;
    } else if (bid < 2048) {
        int sub = bid - 1024;
        size_t i = ((size_t)sub * 8192) + (size_t)t * 32;
        #pragma unroll
        for (int h = 0; h < 4; ++h) {
            float4 f0 = *(const float4*)(adj + i + h * 8);
            float4 f1 = *(const float4*)(adj + i + h * 8 + 4);
            short8 v;
            v[0] = (short)f2bf_bits(f0.x); v[1] = (short)f2bf_bits(f0.y);
            v[2] = (short)f2bf_bits(f0.z); v[3] = (short)f2bf_bits(f0.w);
            v[4] = (short)f2bf_bits(f1.x); v[5] = (short)f2bf_bits(f1.y);
            v[6] = (short)f2bf_bits(f1.z); v[7] = (short)f2bf_bits(f1.w);
            *(short8*)(adjB + i + h * 8) = v;
        }
    } else {
        int idx = bid - 2048;               // 0..1791
        int m   = idx >> 6;                 // matrix 0..27
        int sub = idx & 63;
        int bx = sub & 7, by = sub >> 3;
        const float* S; int R;
        if (m < 2)       { S = w_first + (size_t)m * 130 * 256; R = 130; }
        else if (m < 26) { S = w_mid + (size_t)(m - 2) * 65536; R = 256; }
        else             { S = w_last + (size_t)(m - 26) * 65536; R = 256; }
        bf16* D = wT + (size_t)m * 65536;
        int tx = t & 31, ty = t >> 5;
        int c0 = bx * 32, r0 = by * 32;
        #pragma unroll
        for (int k = 0; k < 4; ++k) {
            int r = r0 + ty + 8 * k;
            tbuf[ty + 8 * k][tx] = (r < R) ? S[(size_t)r * 256 + c0 + tx] : 0.f;
        }
        __syncthreads();
        #pragma unroll
        for (int k = 0; k < 4; ++k) {
            int c = c0 + ty + 8 * k;
            D[(size_t)c * 256 + r0 + tx] = __float2bfloat16(tbuf[tx][ty + 8 * k]);
        }
    }
}

// ======== S: x = combine(gprev + Y0..Y3 + b1 + b2 [+res][relu]) ; [g1|g2T] = x @ wcat ========
// single-phase: stage ALL weights (64 KB, 4 K-planes) + full A tile (16 KB), 1 barrier, 32 MFMA.
// 512 blocks 1-D (XCD-swizzled): lin = ct(4) + 4*rt(128). 256 threads.
__global__ __launch_bounds__(256, 2) void s_kernel(const bf16* __restrict__ gprev,
                                                   const bf16* __restrict__ Yb,
                                                   const float* __restrict__ bias1,
                                                   const float* __restrict__ bias2,
                                                   const bf16* __restrict__ res,
                                                   int relu,
                                                   const bf16* __restrict__ wcat,
                                                   bf16* __restrict__ xR,
                                                   bf16* __restrict__ g1out,
                                                   bf16* __restrict__ g2T) {
    __shared__ char lds[81920];         // Bl: 4 planes x 16 KB @0 ; Al: 4 planes x 4 KB @65536
    char* Bl = lds;
    char* Al = lds + 65536;
    int tid = threadIdx.x;
    int bid = blockIdx.x;
    int lin = (bid & 7) * 64 + (bid >> 3);
    int ct = lin & 3, rt = lin >> 2;
    int lane = tid & 63, w = tid >> 6;
    int wr = w >> 1, wc = w & 1;       // wave: 16 rows x 64 outfeats
    int row16 = lane & 15, kg = lane >> 4;

    // ---- stage all weights: plane p holds K-chunk p (64 wide), rows 0..127, 128B rows swizzled ----
    #pragma unroll
    for (int rnd = 0; rnd < 16; ++rnd) {
        int plane = rnd >> 2;
        int dp = (rnd & 3) * 4096 + tid * 16;   // within-plane byte
        int row = dp >> 7;                       // 0..127
        int cb = dp & 127;
        int sc = (cb ^ ((row & 7) << 4)) >> 1;
        __builtin_amdgcn_global_load_lds(
            (const __attribute__((address_space(1))) void*)(wcat + (size_t)(ct * 128 + row) * 256 + plane * 64 + sc),
            (__attribute__((address_space(3))) void*)(Bl + plane * 16384 + (rnd & 3) * 4096 + (w << 10)),
            16, 0, 0);
    }

    // ---- A combine: 4 planes, per thread one short8 per plane ----
    {
        int arow = tid >> 3;                 // 0..31
        int acb  = (tid * 16) & 127;
        int ridx = rt * 32 + arow;
        int awb  = arow * 128 + (acb ^ ((arow & 7) << 4));
        #pragma unroll
        for (int rnd = 0; rnd < 4; ++rnd) {
            int gcol = rnd * 64 + (acb >> 1);
            size_t off = (size_t)ridx * 256 + gcol;
            short8 pk;
            if (Yb) {
                short8 gv  = *(const short8*)(gprev + off);
                short8 y0v = *(const short8*)(Yb + off);
                short8 y1v = *(const short8*)(Yb + YSTR + off);
                short8 y2v = *(const short8*)(Yb + 2 * YSTR + off);
                short8 y3v = *(const short8*)(Yb + 3 * YSTR + off);
                short8 rv = {};
                if (res) rv = *(const short8*)(res + off);
                #pragma unroll
                for (int j = 0; j < 8; ++j) {
                    float f = bf2f((unsigned short)gv[j]) + bf2f((unsigned short)y0v[j])
                            + bf2f((unsigned short)y1v[j]) + bf2f((unsigned short)y2v[j])
                            + bf2f((unsigned short)y3v[j])
                            + bias1[gcol + j] + bias2[gcol + j];
                    if (res)  f += bf2f((unsigned short)rv[j]);
                    if (relu) f = fmaxf(f, 0.f);
                    pk[j] = (short)f2bf_bits(f);
                }
            } else {
                pk = *(const short8*)(gprev + off);
            }
            if (ct == 0) *(short8*)(xR + off) = pk;
            *(short8*)(Al + rnd * 4096 + awb) = pk;
        }
    }

    asm volatile("s_waitcnt vmcnt(0) lgkmcnt(0)" ::: "memory");
    __builtin_amdgcn_s_barrier();

    f32x4 acc[4] = {};
    int arow = wr * 16 + row16;
    #pragma unroll
    for (int kk = 0; kk < 8; ++kk) {
        int plane = kk >> 1, kk2 = kk & 1;
        int kof = kk2 * 64 + kg * 16;
        short8 a = *(const short8*)(Al + plane * 4096 + arow * 128 + (kof ^ ((arow & 7) << 4)));
        #pragma unroll
        for (int nf = 0; nf < 4; ++nf) {
            int fr = wc * 64 + nf * 16 + row16;
            short8 bfr = *(const short8*)(Bl + plane * 16384 + fr * 128 + (kof ^ ((fr & 7) << 4)));
            acc[nf] = __builtin_amdgcn_mfma_f32_16x16x32_bf16(a, bfr, acc[nf], 0, 0, 0);
        }
    }

    int cbase = ct * 128 + wc * 64;
    int rb = rt * 32 + wr * 16 + kg * 4;
    if (cbase < 256) {
        #pragma unroll
        for (int nf = 0; nf < 4; ++nf) {
            int c = cbase + nf * 16 + row16;
            #pragma unroll
            for (int j = 0; j < 4; ++j)
                *reinterpret_cast<unsigned short*>(&g1out[(size_t)(rb + j) * 256 + c]) = f2bf_bits(acc[nf][j]);
        }
    } else {
        #pragma unroll
        for (int nf = 0; nf < 4; ++nf) {
            int c = cbase - 256 + nf * 16 + row16;
            ushort4v pk;
            #pragma unroll
            for (int j = 0; j < 4; ++j) pk[j] = f2bf_bits(acc[nf][j]);
            *(ushort4v*)(g2T + (size_t)c * 4096 + rb) = pk;
        }
    }
}

// ======== B: Y[ks] = adj[:, ks quarter] @ g2 — BM=128, BN=64, split-K=4 ========
// 3-deep counted-vmcnt pipeline, triple-buffered LDS (3 x 24 KB).
// 512 blocks 1-D (XCD-swizzled): lin = ct(4) + 4*(rt(16) + 16*z(8)), z = b*4+ks. 256 threads.
__global__ __launch_bounds__(256, 2) void adjb_kernel(const bf16* __restrict__ adjB,
                                                      const bf16* __restrict__ g2T,
                                                      bf16* __restrict__ Ybase) {
    __shared__ char lds[73728];         // buf i @ i*24576: A 16 KB, B 8 KB @ +16384
    int tid = threadIdx.x;
    int bid = blockIdx.x;
    int lin = (bid & 7) * 64 + (bid >> 3);
    int ct = lin & 3, rt = (lin >> 2) & 15, z = lin >> 6;
    int b = z >> 2, ks = z & 3;
    const bf16* Aadj = adjB + (size_t)b * NN * NN + (size_t)(rt * 128) * NN + ks * 512;
    const bf16* Bg   = g2T + (size_t)(ct * 64) * 4096 + b * NN + ks * 512;
    bf16* Yo = Ybase + (size_t)ks * YSTR;
    int lane = tid & 63, w = tid >> 6;
    int wr = w >> 1, wc = w & 1;       // wave tile: 64 rows x 32 cols
    int row16 = lane & 15, kg = lane >> 4;
    f32x4 acc[4][2] = {};

    #define STAGE(BUF, IT)                                                                \
        {                                                                                 \
            int k0 = (IT) * 64;                                                           \
            _Pragma("unroll")                                                             \
            for (int rnd = 0; rnd < 4; ++rnd) {                                           \
                int d = tid * 16 + rnd * 4096;                                            \
                int row = d >> 7, cb = d & 127;                                           \
                int sc = (cb ^ ((row & 7) << 4)) >> 1;                                    \
                __builtin_amdgcn_global_load_lds(                                         \
                    (const __attribute__((address_space(1))) void*)(Aadj + (size_t)row * NN + k0 + sc), \
                    (__attribute__((address_space(3))) void*)(lds + (BUF) * 24576 + rnd * 4096 + (w << 10)), \
                    16, 0, 0);                                                            \
            }                                                                             \
            _Pragma("unroll")                                                             \
            for (int rnd = 0; rnd < 2; ++rnd) {                                           \
                int d = tid * 16 + rnd * 4096;                                            \
                int row = d >> 7, cb = d & 127;                                           \
                int sc = (cb ^ ((row & 7) << 4)) >> 1;                                    \
                __builtin_amdgcn_global_load_lds(                                         \
                    (const __attribute__((address_space(1))) void*)(Bg + (size_t)row * 4096 + k0 + sc), \
                    (__attribute__((address_space(3))) void*)(lds + (BUF) * 24576 + 16384 + rnd * 4096 + (w << 10)), \
                    16, 0, 0);                                                            \
            }                                                                             \
        }

    #define MFMA_STEP(BUF)                                                                \
        _Pragma("unroll")                                                                 \
        for (int kk = 0; kk < 2; ++kk) {                                                  \
            short8 a[4], bfr[2];                                                          \
            _Pragma("unroll")                                                             \
            for (int mf = 0; mf < 4; ++mf) {                                              \
                int row = wr * 64 + mf * 16 + row16;                                      \
                a[mf] = *(const short8*)(lds + (BUF) * 24576 + row * 128 +                \
                          (((kk * 64) + kg * 16) ^ ((row & 7) << 4)));                    \
            }                                                                             \
            _Pragma("unroll")                                                             \
            for (int nf = 0; nf < 2; ++nf) {                                              \
                int fr = wc * 32 + nf * 16 + row16;                                       \
                bfr[nf] = *(const short8*)(lds + (BUF) * 24576 + 16384 + fr * 128 +       \
                          (((kk * 64) + kg * 16) ^ ((fr & 7) << 4)));                     \
            }                                                                             \
            _Pragma("unroll")                                                             \
            for (int mf = 0; mf < 4; ++mf)                                                \
                _Pragma("unroll")                                                         \
                for (int nf = 0; nf < 2; ++nf)                                            \
                    acc[mf][nf] = __builtin_amdgcn_mfma_f32_16x16x32_bf16(a[mf], bfr[nf], acc[mf][nf], 0, 0, 0); \
        }

    #define ADJB_ITER(BUF, SBUF, DOSTAGE, CNT)                                            \
        if (DOSTAGE) { STAGE(SBUF, SIT); }                                                \
        asm volatile("s_waitcnt vmcnt(" #CNT ")" ::: "memory");                           \
        __builtin_amdgcn_s_barrier();                                                     \
        MFMA_STEP(BUF);                                                                   \
        __builtin_amdgcn_s_barrier();

    STAGE(0, 0);
    STAGE(1, 1);
    { enum { SIT = 2 }; ADJB_ITER(0, 2, 1, 12) }
    { enum { SIT = 3 }; ADJB_ITER(1, 0, 1, 12) }
    { enum { SIT = 4 }; ADJB_ITER(2, 1, 1, 12) }
    { enum { SIT = 5 }; ADJB_ITER(0, 2, 1, 12) }
    { enum { SIT = 6 }; ADJB_ITER(1, 0, 1, 12) }
    { enum { SIT = 7 }; ADJB_ITER(2, 1, 1, 12) }
    { enum { SIT = 0 }; ADJB_ITER(0, 0, 0, 6) }
    { enum { SIT = 0 }; ADJB_ITER(1, 0, 0, 0) }

    #pragma unroll
    for (int mf = 0; mf < 4; ++mf) {
        #pragma unroll
        for (int nf = 0; nf < 2; ++nf) {
            int c  = ct * 64 + wc * 32 + nf * 16 + row16;
            int r0 = b * NN + rt * 128 + wr * 64 + mf * 16 + kg * 4;
            #pragma unroll
            for (int j = 0; j < 4; ++j)
                *reinterpret_cast<unsigned short*>(&Yo[(size_t)(r0 + j) * 256 + c]) = f2bf_bits(acc[mf][nf][j]);
        }
    }
    #undef STAGE
    #undef MFMA_STEP
    #undef ADJB_ITER
}

// ======== head: z = g1 + ΣY + b_last ; gcn_pred = z@w_fc + b_fc ; outputs; zero lap accumulators ========
__global__ void head_kernel(const bf16* __restrict__ g1, const bf16* __restrict__ Yb,
                            const float* __restrict__ b_last,
                            const float* __restrict__ w_fc, const float* __restrict__ b_fc,
                            const float* __restrict__ base_point, const float* __restrict__ point_mask,
                            float* __restrict__ out, float* __restrict__ dpts) {
    if (blockIdx.x == 0 && threadIdx.x < 2)
        out[4 * BB * NN + threadIdx.x] = 0.f;
    int row = blockIdx.x * 256 + threadIdx.x;
    float s0 = b_fc[0], s1 = b_fc[1];
    for (int d = 0; d < 256; d += 8) {
        size_t off = (size_t)row * 256 + d;
        short8 a = *(const short8*)(g1 + off);
        float zv[8];
        #pragma unroll
        for (int j = 0; j < 8; ++j) zv[j] = bf2f((unsigned short)a[j]);
        #pragma unroll
        for (int p = 0; p < 4; ++p) {
            short8 yv = *(const short8*)(Yb + (size_t)p * YSTR + off);
            #pragma unroll
            for (int j = 0; j < 8; ++j) zv[j] += bf2f((unsigned short)yv[j]);
        }
        #pragma unroll
        for (int j = 0; j < 8; ++j) {
            float z = zv[j] + b_last[d + j] + b_last[256 + d + j];
            s0 += z * w_fc[(d + j) * 2 + 0];
            s1 += z * w_fc[(d + j) * 2 + 1];
        }
    }
    float m  = point_mask[row];
    float p0 = base_point[row * 2 + 0] + s0 * m;
    float p1 = base_point[row * 2 + 1] + s1 * m;
    out[row * 2 + 0] = p0;
    out[row * 2 + 1] = p1;
    out[2 * BB * NN + row * 2 + 0] = s0;
    out[2 * BB * NN + row * 2 + 1] = s1;
    dpts[row * 2 + 0] = s0 * m;
    dpts[row * 2 + 1] = s1 * m;
}

// ======== lap: t = sqrt(|d - adj@d|^2 + 1e-10) per row; block-reduce; atomicAdd mean ========
__global__ void lap_rows(const bf16* __restrict__ adjB, const float* __restrict__ dpts,
                         float* __restrict__ outlap) {
    __shared__ float sd[4];
    int w    = threadIdx.x >> 6;
    int lane = threadIdx.x & 63;
    int row  = blockIdx.x * 4 + w;
    int b = row >> 11, n = row & 2047;
    const bf16* ar = adjB + (size_t)b * NN * NN + (size_t)n * NN;
    const float* db = dpts + (size_t)b * NN * 2;
    float s0 = 0.f, s1 = 0.f;
    for (int k4 = 0; k4 < 4; ++k4) {
        int k = k4 * 512 + lane * 8;
        short8 av = *(const short8*)(ar + k);
        #pragma unroll
        for (int j = 0; j < 8; ++j) {
            float a = bf2f((unsigned short)av[j]);
            float2 dv = *(const float2*)(db + (k + j) * 2);
            s0 += a * dv.x;
            s1 += a * dv.y;
        }
    }
    for (int off = 32; off; off >>= 1) {
        s0 += __shfl_xor(s0, off);
        s1 += __shfl_xor(s1, off);
    }
    if (lane == 0) {
        float e0 = dpts[(size_t)row * 2 + 0] - s0;
        float e1 = dpts[(size_t)row * 2 + 1] - s1;
        sd[w] = sqrtf(e0 * e0 + e1 * e1 + 1e-10f);
    }
    __syncthreads();
    if (threadIdx.x == 0) {
        float s = (sd[0] + sd[1] + sd[2] + sd[3]) * (1.f / (float)NN);
        atomicAdd(&outlap[b], s);
    }
}

extern "C" void kernel_launch(void* const* d_in, const int* in_sizes, int n_in,
                              void* d_out, int out_size, void* d_ws, size_t ws_size,
                              hipStream_t stream) {
    const float* features   = (const float*)d_in[0];
    const float* base_point = (const float*)d_in[1];
    const float* adj        = (const float*)d_in[2];
    const float* point_mask = (const float*)d_in[3];
    const float* w_first    = (const float*)d_in[4];
    const float* b_first    = (const float*)d_in[5];
    const float* w_mid      = (const float*)d_in[6];
    const float* b_mid      = (const float*)d_in[7];
    const float* w_last     = (const float*)d_in[8];
    const float* b_last     = (const float*)d_in[9];
    const float* w_fc       = (const float*)d_in[10];
    const float* b_fc       = (const float*)d_in[11];
    float* out = (float*)d_out;
    char* W = (char*)d_ws;

    bf16* adjB   = (bf16*)W;                          // 16.78 MB
    bf16* wT     = (bf16*)(W + 16777216);             // 3.67 MB
    bf16* x0p    = (bf16*)(W + 20447232);
    bf16* g1b[2] = { (bf16*)(W + 22544384), (bf16*)(W + 24641536) };
    bf16* g2T    = (bf16*)(W + 26738688);
    bf16* Yb     = (bf16*)(W + 28835840);             // 4 partials x 2 MB
    bf16* xsl[2] = { (bf16*)(W + 37224448), (bf16*)(W + 39321600) };
    bf16* xscr   = (bf16*)(W + 41418752);
    float* dpts  = (float*)(W + 43515904);

    prep_kernel<<<3840, 256, 0, stream>>>(adj, adjB, features, base_point, x0p,
                                          w_first, w_mid, w_last, wT);

    // L0
    s_kernel<<<512, 256, 0, stream>>>(x0p, nullptr, nullptr, nullptr, nullptr, 0,
                                      wT, xscr, g1b[0], g2T);
    adjb_kernel<<<512, 256, 0, stream>>>(adjB, g2T, Yb);

    for (int k = 1; k < 14; ++k) {
        const float *bb1, *bb2;
        const bf16* resp = nullptr;
        bf16* xw;
        int rl;
        if (k == 1) {
            bb1 = b_first; bb2 = b_first + 256; rl = 0; xw = xsl[0];
        } else if ((k & 1) == 0) {
            int m = (k - 2) / 2;
            bb1 = b_mid + (size_t)m * 1024; bb2 = bb1 + 256;
            rl = 1; xw = xscr;
        } else {
            int m = (k - 3) / 2;
            bb1 = b_mid + (size_t)m * 1024 + 512; bb2 = bb1 + 256;
            rl = 1;
            resp = xsl[m & 1];
            xw   = xsl[((k - 1) / 2) & 1];
        }
        s_kernel<<<512, 256, 0, stream>>>(g1b[(k - 1) & 1], Yb, bb1, bb2, resp, rl,
                                          wT + (size_t)2 * k * 65536, xw, g1b[k & 1], g2T);
        adjb_kernel<<<512, 256, 0, stream>>>(adjB, g2T, Yb);
    }

    head_kernel<<<16, 256, 0, stream>>>(g1b[1], Yb, b_last, w_fc, b_fc,
                                        base_point, point_mask, out, dpts);
    lap_rows<<<1024, 256, 0, stream>>>(adjB, dpts, out + 4 * BB * NN);
}